// Round 9
// baseline (538.656 us; speedup 1.0000x reference)
//
#include <hip/hip_runtime.h>

typedef _Float16 f16x8 __attribute__((ext_vector_type(8)));
typedef _Float16 f16x4 __attribute__((ext_vector_type(4)));
typedef _Float16 f16x2 __attribute__((ext_vector_type(2)));
typedef float f32x4 __attribute__((ext_vector_type(4)));

#define NSEQ 2048
#define DMODEL 2048
#define NHEADS 32
#define NKV 8
#define DK 64
#define MFMA16(a, b, c) __builtin_amdgcn_mfma_f32_16x16x32_f16(a, b, c, 0, 0, 0)

// async global->LDS, 16B per lane; LDS dest is wave-uniform base + lane*16
__device__ __forceinline__ void gload16(const void* g, void* l) {
    __builtin_amdgcn_global_load_lds(
        (const __attribute__((address_space(1))) void*)g,
        (__attribute__((address_space(3))) void*)l, 16, 0, 0);
}

// ---------------- elementwise f32 -> f16 ----------------
__global__ void cvt_f32_f16(const float* __restrict__ in, _Float16* __restrict__ out, int n4) {
    int i = blockIdx.x * blockDim.x + threadIdx.x;
    int stride = gridDim.x * blockDim.x;
    for (; i < n4; i += stride) {
        float4 v = ((const float4*)in)[i];
        f16x4 h;
        h[0] = (_Float16)v.x; h[1] = (_Float16)v.y;
        h[2] = (_Float16)v.z; h[3] = (_Float16)v.w;
        ((f16x4*)out)[i] = h;
    }
}

// ---------------- transpose + convert: in f32 [R][C] -> out f16 [C][R] ----------------
__global__ __launch_bounds__(256) void transpose_cvt(const float* __restrict__ in,
                                                     _Float16* __restrict__ out,
                                                     int R, int C) {
    __shared__ float tile[32][33];
    int c0 = blockIdx.x * 32, r0 = blockIdx.y * 32;
    int tx = threadIdx.x, ty = threadIdx.y; // (32,8)
#pragma unroll
    for (int i = 0; i < 4; i++) {
        int r = r0 + ty + i * 8;
        tile[ty + i * 8][tx] = in[(long long)r * C + c0 + tx];
    }
    __syncthreads();
#pragma unroll
    for (int i = 0; i < 4; i++) {
        int c = c0 + ty + i * 8;
        out[(long long)c * R + r0 + tx] = (_Float16)tile[tx][ty + i * 8];
    }
}

// ---------------- transpose f16 [R][C] -> f16 [C][R] ----------------
__global__ __launch_bounds__(256) void transpose16(const _Float16* __restrict__ in,
                                                   _Float16* __restrict__ out,
                                                   int R, int C) {
    __shared__ _Float16 tile[32][34];
    int c0 = blockIdx.x * 32, r0 = blockIdx.y * 32;
    int tx = threadIdx.x, ty = threadIdx.y; // (32,8)
#pragma unroll
    for (int i = 0; i < 4; i++) {
        int r = r0 + ty + i * 8;
        tile[ty + i * 8][tx] = in[(long long)r * C + c0 + tx];
    }
    __syncthreads();
#pragma unroll
    for (int i = 0; i < 4; i++) {
        int c = c0 + ty + i * 8;
        out[(long long)c * R + r0 + tx] = tile[tx][ty + i * 8];
    }
}

// ---------------- RoPE cos/sin table ----------------
__global__ void rope_table(float2* __restrict__ cs) {
    int idx = blockIdx.x * blockDim.x + threadIdx.x; // 65536 total
    int n = idx >> 5, j = idx & 31;
    float e = (2.0f * j) / 64.0f;
    float invf = 1.0f / powf(10000.0f, e);
    float ang = (float)n * invf;
    float2 v; v.x = cosf(ang); v.y = sinf(ang);
    cs[idx] = v;
}

// ---------------- RoPE apply f16->f16 for K (ncols=512) ----------------
__global__ void rope_apply16(const _Float16* __restrict__ in, const float2* __restrict__ cs,
                             _Float16* __restrict__ out) {
    int idx = blockIdx.x * blockDim.x + threadIdx.x; // 2048*256
    int n = idx >> 8, rem = idx & 255;
    int hk = rem >> 5, j = rem & 31;
    float2 c = cs[n * 32 + j];
    long long base = (long long)n * 512 + hk * 64;
    float x1 = (float)in[base + j], x2 = (float)in[base + j + 32];
    out[base + j]      = (_Float16)(x1 * c.x - x2 * c.y);
    out[base + j + 32] = (_Float16)(x2 * c.x + x1 * c.y);
}

// ---------------- GEMM (m97 structure): C[M,N] = A[M,K] @ Bt[N,K]^T ----------------
template <int BM, int BN, int MF, int NF, typename OutT>
__global__ __launch_bounds__(256) void gemm_lds(const _Float16* __restrict__ Ap,
                                                const _Float16* __restrict__ Bt,
                                                OutT* __restrict__ C,
                                                int K, int lda, int ldb, int ldc) {
    __shared__ __align__(16) _Float16 As[BM * 32];
    __shared__ __align__(16) _Float16 Bs[BN * 32];

    const int tid = threadIdx.x;
    const int lane = tid & 63, w = tid >> 6;
    constexpr int WC = BN / (NF * 16);
    const int wr = w / WC, wc = w % WC;
    const int wm = wr * MF * 16, wn = wc * NF * 16;
    const int am = lane & 15;
    const int g = lane >> 4;

    f32x4 acc[MF][NF] = {};

    const long long a_row0 = (long long)blockIdx.y * BM * lda;
    const long long b_row0 = (long long)blockIdx.x * BN * ldb;

    const int srow = lane >> 2;        // staging: row within 16-row group
    const int scol = (lane & 3) * 8;   // staging: halfs offset within row

    for (int kt = 0; kt < K; kt += 32) {
#pragma unroll
        for (int q = 0; q < BM / 64; q++) {
            const int row = w * (BM / 4) + q * 16 + srow;
            gload16(Ap + a_row0 + (long long)row * lda + kt + scol,
                    &As[w * (BM * 8) + q * 512]);
        }
#pragma unroll
        for (int q = 0; q < BN / 64; q++) {
            const int row = w * (BN / 4) + q * 16 + srow;
            gload16(Bt + b_row0 + (long long)row * ldb + kt + scol,
                    &Bs[w * (BN * 8) + q * 512]);
        }
        __syncthreads();

        f16x8 af[MF], bf[NF];
#pragma unroll
        for (int m = 0; m < MF; m++) af[m] = *(const f16x8*)&As[(wm + m * 16 + am) * 32 + g * 8];
#pragma unroll
        for (int n = 0; n < NF; n++) bf[n] = *(const f16x8*)&Bs[(wn + n * 16 + am) * 32 + g * 8];
#pragma unroll
        for (int m = 0; m < MF; m++)
#pragma unroll
            for (int n = 0; n < NF; n++)
                acc[m][n] = MFMA16(af[m], bf[n], acc[m][n]);
        __syncthreads();
    }

    const int rb = blockIdx.y * BM + wm + (lane >> 4) * 4;
    const int cb = blockIdx.x * BN + wn + am;
#pragma unroll
    for (int m = 0; m < MF; m++)
#pragma unroll
        for (int n = 0; n < NF; n++)
#pragma unroll
            for (int j = 0; j < 4; j++)
                C[(long long)(rb + m * 16 + j) * ldc + cb + n * 16] = (OutT)acc[m][n][j];
}

// ---------------- fused attention v6: v5 dataflow at 16 waves/block, 100% occupancy --------
// 1024 thr / 16 waves; block = 16 Q-rows. Wave w: QK kcols [w*128,+128) (8 unrolled iters),
// stores row w (8 x 1KB contiguous), PV d-quarter (w&3) x k-quarter (w>>2), fp16 partials.
// LDS: E 64KB + Ored 8KB + lsum/s_inv ~1.1KB = 73.1KB -> 2 blocks/CU = 32 waves/CU.
__global__ __launch_bounds__(1024, 8) void fused_attn(
    const _Float16* __restrict__ Qraw, // [2048][2048] pre-rope fp16
    const float2*  __restrict__ cs,    // [2048][32]
    const _Float16* __restrict__ Kh,   // [2048][512] roped
    const _Float16* __restrict__ Vt,   // [512][2048]
    float* __restrict__ attn,          // [32][2048][2048]
    _Float16* __restrict__ AVh)        // [2048][2048]
{
    __shared__ __align__(16) _Float16 E[16 * 2048];    // 64 KB
    __shared__ __align__(16) _Float16 Ored[4][16][64]; // 8 KB (fp16 partials, |.|~30)
    __shared__ float lsum[16][16];
    __shared__ float s_inv[16];

    const int h = blockIdx.y, q0 = blockIdx.x * 16;
    const int kvh = h >> 2;
    const int tid = threadIdx.x, lane = tid & 63, w = tid >> 6;
    const int g = lane >> 4, c = lane & 15;

    // ---- Q fragment (B-operand, Q-row = c) + in-register RoPE ----
    const _Float16* qp = Qraw + (long long)(q0 + c) * DMODEL + h * 64;
    f16x8 q0v = *(const f16x8*)(qp + g * 8);
    f16x8 q1v = *(const f16x8*)(qp + 32 + g * 8);
    const float2* csp = cs + (q0 + c) * 32 + g * 8;
    f16x8 qa, qb_;
#pragma unroll
    for (int e = 0; e < 8; e++) {
        float2 cv = csp[e];
        float x1 = (float)q0v[e], x2 = (float)q1v[e];
        qa[e]  = (_Float16)(x1 * cv.x - x2 * cv.y);
        qb_[e] = (_Float16)(x2 * cv.x + x1 * cv.y);
    }

    const _Float16* Kbase = Kh + kvh * 64;
    const _Float16* Vbase = Vt + (long long)(kvh * 64) * NSEQ;
    const int swz = (c & 7) << 4;
    const int kw = w * 128;

    // ---- QK over this wave's 128-col strip: e -> E, row sums in regs ----
    float l = 0.f;
#pragma unroll
    for (int t2 = 0; t2 < 8; t2++) {
        const int kcolb = kw + t2 * 16;
        const _Float16* kp = Kbase + (long long)(kcolb + c) * 512;
        f16x8 kb0 = *(const f16x8*)(kp + g * 8);
        f16x8 kb1 = *(const f16x8*)(kp + 32 + g * 8);
        f32x4 acc = {0.f, 0.f, 0.f, 0.f};
        acc = MFMA16(kb0, qa, acc);
        acc = MFMA16(kb1, qb_, acc);
        float e0 = __expf(fminf(acc[0] * 0.125f, 11.f));
        float e1 = __expf(fminf(acc[1] * 0.125f, 11.f));
        float e2 = __expf(fminf(acc[2] * 0.125f, 11.f));
        float e3 = __expf(fminf(acc[3] * 0.125f, 11.f));
        l += (e0 + e1) + (e2 + e3);
        f16x2 p01; p01[0] = (_Float16)e0; p01[1] = (_Float16)e1;
        f16x2 p23; p23[0] = (_Float16)e2; p23[1] = (_Float16)e3;
        int b0 = c * 4096 + (((kcolb + 4 * g) * 2) ^ swz);
        *(f16x2*)((char*)E + b0) = p01;
        *(f16x2*)((char*)E + b0 + 4) = p23;
    }
    l += __shfl_xor(l, 16, 64);
    l += __shfl_xor(l, 32, 64);
    if (lane < 16) lsum[w][lane] = l;
    __syncthreads();
    if (tid < 16) {
        float S = 0.f;
#pragma unroll
        for (int w2 = 0; w2 < 16; w2++) S += lsum[w2][tid];
        s_inv[tid] = 1.0f / S;
    }
    __syncthreads();

    // ---- attn stores: wave w writes row w, 8 x 1KB-contiguous wave-instrs ----
    {
        const int r = w;
        const float inv = s_inv[r];
        const int swr = (r & 7) << 4;
        float* arow = attn + ((long long)h * NSEQ + q0 + r) * NSEQ;
        const char* erow = (const char*)E + r * 4096;
#pragma unroll
        for (int i = 0; i < 8; i++) {
            f16x4 ev = *(const f16x4*)(erow + ((i * 512 + lane * 8) ^ swr));
            f32x4 o;
            o[0] = (float)ev[0] * inv; o[1] = (float)ev[1] * inv;
            o[2] = (float)ev[2] * inv; o[3] = (float)ev[3] * inv;
            *(f32x4*)(arow + i * 256 + lane * 4) = o;
        }
    }

    // ---- PV: wave w -> d-quarter dt = w&3, k-quarter kq = w>>2 ----
    const int dt = w & 3, kq = w >> 2;
    f32x4 opv = {0.f, 0.f, 0.f, 0.f};
    const _Float16* vrow = Vbase + (long long)(dt * 16 + c) * NSEQ + kq * 512;
    const char* erowc = (const char*)E + c * 4096;
#pragma unroll 4
    for (int kk = 0; kk < 512; kk += 32) {
        f16x8 pa = *(const f16x8*)(erowc + (((kq * 512 + kk + g * 8) * 2) ^ swz));
        f16x8 vb = *(const f16x8*)(vrow + kk + g * 8);
        opv = MFMA16(pa, vb, opv);
    }
#pragma unroll
    for (int j = 0; j < 4; j++) Ored[kq][4 * g + j][dt * 16 + c] = (_Float16)opv[j];
    __syncthreads();

    // ---- merge quarters -> AVh: wave w handles row w, d = lane ----
    {
        const int r = w, d = lane;
        float a = (float)Ored[0][r][d] + (float)Ored[1][r][d] +
                  (float)Ored[2][r][d] + (float)Ored[3][r][d];
        AVh[(long long)(q0 + r) * DMODEL + h * 64 + d] = (_Float16)(a * s_inv[r]);
    }
}

extern "C" void kernel_launch(void* const* d_in, const int* in_sizes, int n_in,
                              void* d_out, int out_size, void* d_ws, size_t ws_size,
                              hipStream_t stream) {
    const float* x  = (const float*)d_in[0];
    const float* Wq = (const float*)d_in[1];
    const float* Wk = (const float*)d_in[2];
    const float* Wv = (const float*)d_in[3];
    const float* Wo = (const float*)d_in[4];
    float* out = (float*)d_out;
    float* attn = out + (size_t)NSEQ * DMODEL;

    char* w = (char*)d_ws;
    auto alloc = [&](size_t bytes) { char* p = w; w += (bytes + 255) & ~(size_t)255; return p; };
    const size_t MD = (size_t)NSEQ * DMODEL;        // 4M elems
    const size_t MKV = (size_t)NSEQ * NKV * DK;     // 1M elems
    _Float16* xh   = (_Float16*)alloc(MD * 2);
    _Float16* WqT  = (_Float16*)alloc(MD * 2);
    _Float16* WkT  = (_Float16*)alloc(MKV * 2);
    _Float16* WvT  = (_Float16*)alloc(MKV * 2);
    _Float16* WoT  = (_Float16*)alloc(MD * 2);
    float2*   cs   = (float2*)alloc((size_t)NSEQ * 32 * sizeof(float2));
    _Float16* Qraw = (_Float16*)alloc(MD * 2);
    _Float16* Kraw = (_Float16*)alloc(MKV * 2);
    _Float16* Kh   = (_Float16*)alloc(MKV * 2);
    _Float16* Vh   = (_Float16*)alloc(MKV * 2);
    _Float16* Vt   = (_Float16*)alloc(MKV * 2);
    _Float16* AVh  = xh;   // reuse (xh dead after projections)

    cvt_f32_f16<<<2048, 256, 0, stream>>>(x, xh, (int)(MD / 4));
    transpose_cvt<<<dim3(DMODEL / 32, DMODEL / 32), dim3(32, 8), 0, stream>>>(Wq, WqT, DMODEL, DMODEL);
    transpose_cvt<<<dim3(512 / 32, DMODEL / 32), dim3(32, 8), 0, stream>>>(Wk, WkT, DMODEL, 512);
    transpose_cvt<<<dim3(512 / 32, DMODEL / 32), dim3(32, 8), 0, stream>>>(Wv, WvT, DMODEL, 512);
    transpose_cvt<<<dim3(DMODEL / 32, DMODEL / 32), dim3(32, 8), 0, stream>>>(Wo, WoT, DMODEL, DMODEL);
    rope_table<<<256, 256, 0, stream>>>(cs);

    gemm_lds<128, 128, 4, 4, _Float16><<<dim3(16, 16), 256, 0, stream>>>(xh, WqT, Qraw, DMODEL, DMODEL, DMODEL, DMODEL);
    gemm_lds<128, 128, 4, 4, _Float16><<<dim3(4, 16), 256, 0, stream>>>(xh, WkT, Kraw, DMODEL, DMODEL, DMODEL, 512);
    gemm_lds<128, 128, 4, 4, _Float16><<<dim3(4, 16), 256, 0, stream>>>(xh, WvT, Vh, DMODEL, DMODEL, DMODEL, 512);

    rope_apply16<<<2048, 256, 0, stream>>>(Kraw, cs, Kh);
    transpose16<<<dim3(512 / 32, NSEQ / 32), dim3(32, 8), 0, stream>>>(Vh, Vt, NSEQ, 512);

    fused_attn<<<dim3(NSEQ / 16, NHEADS), 1024, 0, stream>>>(Qraw, cs, Kh, Vt, attn, AVh);

    gemm_lds<128, 128, 4, 4, float><<<dim3(16, 16), 256, 0, stream>>>(AVh, WoT, out, DMODEL, DMODEL, DMODEL, DMODEL);
}

// Round 10
// 517.436 us; speedup vs baseline: 1.0410x; 1.0410x over previous
//
#include <hip/hip_runtime.h>

typedef _Float16 f16x8 __attribute__((ext_vector_type(8)));
typedef _Float16 f16x4 __attribute__((ext_vector_type(4)));
typedef _Float16 f16x2 __attribute__((ext_vector_type(2)));
typedef float f32x4 __attribute__((ext_vector_type(4)));

#define NSEQ 2048
#define DMODEL 2048
#define NHEADS 32
#define NKV 8
#define DK 64
#define MFMA16(a, b, c) __builtin_amdgcn_mfma_f32_16x16x32_f16(a, b, c, 0, 0, 0)

// async global->LDS, 16B per lane; LDS dest is wave-uniform base + lane*16
__device__ __forceinline__ void gload16(const void* g, void* l) {
    __builtin_amdgcn_global_load_lds(
        (const __attribute__((address_space(1))) void*)g,
        (__attribute__((address_space(3))) void*)l, 16, 0, 0);
}

// ---------------- elementwise f32 -> f16 ----------------
__global__ void cvt_f32_f16(const float* __restrict__ in, _Float16* __restrict__ out, int n4) {
    int i = blockIdx.x * blockDim.x + threadIdx.x;
    int stride = gridDim.x * blockDim.x;
    for (; i < n4; i += stride) {
        float4 v = ((const float4*)in)[i];
        f16x4 h;
        h[0] = (_Float16)v.x; h[1] = (_Float16)v.y;
        h[2] = (_Float16)v.z; h[3] = (_Float16)v.w;
        ((f16x4*)out)[i] = h;
    }
}

// ---------------- transpose + convert: in f32 [R][C] -> out f16 [C][R] ----------------
__global__ __launch_bounds__(256) void transpose_cvt(const float* __restrict__ in,
                                                     _Float16* __restrict__ out,
                                                     int R, int C) {
    __shared__ float tile[32][33];
    int c0 = blockIdx.x * 32, r0 = blockIdx.y * 32;
    int tx = threadIdx.x, ty = threadIdx.y; // (32,8)
#pragma unroll
    for (int i = 0; i < 4; i++) {
        int r = r0 + ty + i * 8;
        tile[ty + i * 8][tx] = in[(long long)r * C + c0 + tx];
    }
    __syncthreads();
#pragma unroll
    for (int i = 0; i < 4; i++) {
        int c = c0 + ty + i * 8;
        out[(long long)c * R + r0 + tx] = (_Float16)tile[tx][ty + i * 8];
    }
}

// ---------------- transpose f16 [R][C] (row pitch) -> f16 [C][R] ----------------
__global__ __launch_bounds__(256) void transpose16p(const _Float16* __restrict__ in,
                                                    _Float16* __restrict__ out,
                                                    int R, int C, int pitch) {
    __shared__ _Float16 tile[32][34];
    int c0 = blockIdx.x * 32, r0 = blockIdx.y * 32;
    int tx = threadIdx.x, ty = threadIdx.y; // (32,8)
#pragma unroll
    for (int i = 0; i < 4; i++) {
        int r = r0 + ty + i * 8;
        tile[ty + i * 8][tx] = in[(long long)r * pitch + c0 + tx];
    }
    __syncthreads();
#pragma unroll
    for (int i = 0; i < 4; i++) {
        int c = c0 + ty + i * 8;
        out[(long long)c * R + r0 + tx] = tile[tx][ty + i * 8];
    }
}

// ---------------- RoPE cos/sin table ----------------
__global__ void rope_table(float2* __restrict__ cs) {
    int idx = blockIdx.x * blockDim.x + threadIdx.x; // 65536 total
    int n = idx >> 5, j = idx & 31;
    float e = (2.0f * j) / 64.0f;
    float invf = 1.0f / powf(10000.0f, e);
    float ang = (float)n * invf;
    float2 v; v.x = cosf(ang); v.y = sinf(ang);
    cs[idx] = v;
}

// ---------------- RoPE apply for K: reads K cols of QKV [2048][3072], writes Kh [2048][512] --
__global__ void rope_apply16(const _Float16* __restrict__ QKV, const float2* __restrict__ cs,
                             _Float16* __restrict__ out) {
    int idx = blockIdx.x * blockDim.x + threadIdx.x; // 2048*256
    int n = idx >> 8, rem = idx & 255;
    int hk = rem >> 5, j = rem & 31;
    float2 c = cs[n * 32 + j];
    const _Float16* in = QKV + (long long)n * 3072 + 2048 + hk * 64;
    float x1 = (float)in[j], x2 = (float)in[j + 32];
    long long ob = (long long)n * 512 + hk * 64;
    out[ob + j]      = (_Float16)(x1 * c.x - x2 * c.y);
    out[ob + j + 32] = (_Float16)(x2 * c.x + x1 * c.y);
}

// ---------------- GEMM (m97 structure): C[M,N] = A[M,K] @ Bt[N,K]^T ----------------
template <int BM, int BN, int MF, int NF, typename OutT>
__global__ __launch_bounds__(256) void gemm_lds(const _Float16* __restrict__ Ap,
                                                const _Float16* __restrict__ Bt,
                                                OutT* __restrict__ C,
                                                int K, int lda, int ldb, int ldc) {
    __shared__ __align__(16) _Float16 As[BM * 32];
    __shared__ __align__(16) _Float16 Bs[BN * 32];

    const int tid = threadIdx.x;
    const int lane = tid & 63, w = tid >> 6;
    constexpr int WC = BN / (NF * 16);
    const int wr = w / WC, wc = w % WC;
    const int wm = wr * MF * 16, wn = wc * NF * 16;
    const int am = lane & 15;
    const int g = lane >> 4;

    f32x4 acc[MF][NF] = {};

    const long long a_row0 = (long long)blockIdx.y * BM * lda;
    const long long b_row0 = (long long)blockIdx.x * BN * ldb;

    const int srow = lane >> 2;        // staging: row within 16-row group
    const int scol = (lane & 3) * 8;   // staging: halfs offset within row

    for (int kt = 0; kt < K; kt += 32) {
#pragma unroll
        for (int q = 0; q < BM / 64; q++) {
            const int row = w * (BM / 4) + q * 16 + srow;
            gload16(Ap + a_row0 + (long long)row * lda + kt + scol,
                    &As[w * (BM * 8) + q * 512]);
        }
#pragma unroll
        for (int q = 0; q < BN / 64; q++) {
            const int row = w * (BN / 4) + q * 16 + srow;
            gload16(Bt + b_row0 + (long long)row * ldb + kt + scol,
                    &Bs[w * (BN * 8) + q * 512]);
        }
        __syncthreads();

        f16x8 af[MF], bf[NF];
#pragma unroll
        for (int m = 0; m < MF; m++) af[m] = *(const f16x8*)&As[(wm + m * 16 + am) * 32 + g * 8];
#pragma unroll
        for (int n = 0; n < NF; n++) bf[n] = *(const f16x8*)&Bs[(wn + n * 16 + am) * 32 + g * 8];
#pragma unroll
        for (int m = 0; m < MF; m++)
#pragma unroll
            for (int n = 0; n < NF; n++)
                acc[m][n] = MFMA16(af[m], bf[n], acc[m][n]);
        __syncthreads();
    }

    const int rb = blockIdx.y * BM + wm + (lane >> 4) * 4;
    const int cb = blockIdx.x * BN + wn + am;
#pragma unroll
    for (int m = 0; m < MF; m++)
#pragma unroll
        for (int n = 0; n < NF; n++)
#pragma unroll
            for (int j = 0; j < 4; j++)
                C[(long long)(rb + m * 16 + j) * ldc + cb + n * 16] = (OutT)acc[m][n][j];
}

// ---------------- fused attention v7: LDS-staged K/V (m97 cadence) + v5 store path ----------
// 512 thr / 8 waves; block = 16 Q-rows. 16 chunks x 128 kcols.
// Per chunk: stage K(next) double-buf + V(cur) single-buf via gload16 (pre-swizzled source),
// QK: wave w -> chunk-local kcols [w*16,+16): 2 ds_read_b128 + 2 MFMA + exp -> E (swizzled).
// barrier; PV: wave w -> d-tile (w&3) x col-half (w>>2): ds_reads from E + Vbuf, 2 MFMA; barrier.
// After loop: row-sum merge, row-contiguous attn stores (v5), Ored merge -> AVh.
// LDS: E 64K + Kbuf 32K + Vbuf 16K + Ored 8K + misc ~= 120.6 KB -> 1 block/CU.
__global__ __launch_bounds__(512) void fused_attn(
    const _Float16* __restrict__ QKV,  // [2048][3072], Q = cols 0..2047 (pre-rope)
    const float2*  __restrict__ cs,    // [2048][32]
    const _Float16* __restrict__ Kh,   // [2048][512] roped
    const _Float16* __restrict__ Vt,   // [512][2048]
    float* __restrict__ attn,          // [32][2048][2048]
    _Float16* __restrict__ AVh)        // [2048][2048]
{
    __shared__ __align__(16) _Float16 E[16 * 2048];      // 64 KB
    __shared__ __align__(16) _Float16 Kbuf[2][128 * 64]; // 32 KB (row pitch 128B)
    __shared__ __align__(16) _Float16 Vbuf[64 * 128];    // 16 KB (row pitch 256B)
    __shared__ float Ored[2][16][64];                    // 8 KB
    __shared__ float lsum[8][16], s_inv[16];

    const int h = blockIdx.y, q0 = blockIdx.x * 16;
    const int kvh = h >> 2;
    const int tid = threadIdx.x, lane = tid & 63, w = tid >> 6;
    const int g = lane >> 4, c = lane & 15;
    const int swz = (c & 7) << 4;

    // ---- Q fragment (B-operand, Q-row = c) + in-register RoPE ----
    const _Float16* qp = QKV + (long long)(q0 + c) * 3072 + h * 64;
    f16x8 q0v = *(const f16x8*)(qp + g * 8);
    f16x8 q1v = *(const f16x8*)(qp + 32 + g * 8);
    const float2* csp = cs + (q0 + c) * 32 + g * 8;
    f16x8 qa, qb_;
#pragma unroll
    for (int e = 0; e < 8; e++) {
        float2 cv = csp[e];
        float x1 = (float)q0v[e], x2 = (float)q1v[e];
        qa[e]  = (_Float16)(x1 * cv.x - x2 * cv.y);
        qb_[e] = (_Float16)(x2 * cv.x + x1 * cv.y);
    }

    // staging lane constants
    const int krl = lane >> 3;          // K: row within 8-row group
    const int kcb = (lane & 7) * 16;    // K: col byte
    const int vrl = lane >> 4;          // V: row within 4-row group
    const int vcb = (lane & 15) * 16;   // V: col byte
    const _Float16* Kg = Kh + kvh * 64;
    const _Float16* Vg = Vt + (long long)(kvh * 64) * NSEQ;

    // ---- prologue: stage K chunk 0 into buf 0 ----
#pragma unroll
    for (int q = 0; q < 2; q++) {
        int r = w * 16 + q * 8 + krl;
        gload16(Kg + (long long)r * 512 + ((kcb ^ ((r & 7) << 4)) >> 1),
                (char*)Kbuf[0] + (w * 16 + q * 8) * 128);
    }
    __syncthreads();

    const int dt = w & 3, kh2 = w >> 2;
    float l = 0.f;
    f32x4 opv = {0.f, 0.f, 0.f, 0.f};

#pragma unroll 2
    for (int i = 0; i < 16; i++) {
        const int kc = i * 128;
        const int buf = i & 1;
        // stage K(i+1) (wraps harmlessly at i=15) and V(i)
        {
            const int nkc = ((i + 1) & 15) * 128;
#pragma unroll
            for (int q = 0; q < 2; q++) {
                int r = w * 16 + q * 8 + krl;
                gload16(Kg + (long long)(nkc + r) * 512 + ((kcb ^ ((r & 7) << 4)) >> 1),
                        (char*)Kbuf[buf ^ 1] + (w * 16 + q * 8) * 128);
            }
#pragma unroll
            for (int q = 0; q < 2; q++) {
                int j = w + q * 8;
                int d = j * 4 + vrl;
                gload16(Vg + (long long)d * NSEQ + kc + ((vcb ^ ((d & 7) << 4)) >> 1),
                        (char*)Vbuf + j * 1024);
            }
        }
        // QK: wave w owns chunk-local kcols [w*16, +16)
        {
            const char* kb = (const char*)Kbuf[buf] + (w * 16 + c) * 128;
            f16x8 kb0 = *(const f16x8*)(kb + ((g * 16) ^ swz));
            f16x8 kb1 = *(const f16x8*)(kb + ((64 + g * 16) ^ swz));
            f32x4 acc = {0.f, 0.f, 0.f, 0.f};
            acc = MFMA16(kb0, qa, acc);
            acc = MFMA16(kb1, qb_, acc);
            float e0 = __expf(fminf(acc[0] * 0.125f, 11.f));
            float e1 = __expf(fminf(acc[1] * 0.125f, 11.f));
            float e2 = __expf(fminf(acc[2] * 0.125f, 11.f));
            float e3 = __expf(fminf(acc[3] * 0.125f, 11.f));
            l += (e0 + e1) + (e2 + e3);
            f16x4 p;
            p[0] = (_Float16)e0; p[1] = (_Float16)e1;
            p[2] = (_Float16)e2; p[3] = (_Float16)e3;
            *(f16x4*)((char*)E + c * 4096 + (((kc + w * 16 + 4 * g) * 2) ^ swz)) = p;
        }
        __syncthreads();  // E(i) ready; K(i+1)/V(i) stages drained
        // PV: wave w -> d-tile dt, col-half kh2 of this chunk
        {
            const char* erow = (const char*)E + c * 4096;
            const char* vrow = (const char*)Vbuf + (dt * 16 + c) * 256;
#pragma unroll
            for (int kk = 0; kk < 64; kk += 32) {
                int col = kh2 * 64 + kk + g * 8;
                f16x8 pa = *(const f16x8*)(erow + (((kc + col) * 2) ^ swz));
                f16x8 vb = *(const f16x8*)(vrow + ((col * 2) ^ swz));
                opv = MFMA16(pa, vb, opv);
            }
        }
        __syncthreads();  // Vbuf free for next stage
    }

    // ---- row-sum merge ----
    l += __shfl_xor(l, 16, 64);
    l += __shfl_xor(l, 32, 64);
    if (lane < 16) lsum[w][lane] = l;
    __syncthreads();
    if (tid < 16) {
        float S = 0.f;
#pragma unroll
        for (int w2 = 0; w2 < 8; w2++) S += lsum[w2][tid];
        s_inv[tid] = 1.0f / S;
    }
    __syncthreads();

    // ---- attn stores: wave w writes rows {w, w+8}, 8 x 1KB contiguous each ----
#pragma unroll
    for (int rr2 = 0; rr2 < 2; rr2++) {
        const int r = w + rr2 * 8;
        const float inv = s_inv[r];
        const int swr = (r & 7) << 4;
        float* arow = attn + ((long long)h * NSEQ + q0 + r) * NSEQ;
        const char* erow = (const char*)E + r * 4096;
#pragma unroll
        for (int i = 0; i < 8; i++) {
            f16x4 ev = *(const f16x4*)(erow + ((i * 512 + lane * 8) ^ swr));
            f32x4 o;
            o[0] = (float)ev[0] * inv; o[1] = (float)ev[1] * inv;
            o[2] = (float)ev[2] * inv; o[3] = (float)ev[3] * inv;
            *(f32x4*)(arow + i * 256 + lane * 4) = o;
        }
    }

    // ---- PV merge -> AVh ----
#pragma unroll
    for (int j = 0; j < 4; j++) Ored[kh2][4 * g + j][dt * 16 + c] = opv[j];
    __syncthreads();
    {
        const int r = tid >> 5, d2 = (tid & 31) * 2;
        float a0 = Ored[0][r][d2] + Ored[1][r][d2];
        float a1 = Ored[0][r][d2 + 1] + Ored[1][r][d2 + 1];
        const float iv = s_inv[r];
        f16x2 o; o[0] = (_Float16)(a0 * iv); o[1] = (_Float16)(a1 * iv);
        *(f16x2*)(AVh + (long long)(q0 + r) * DMODEL + h * 64 + d2) = o;
    }
}

extern "C" void kernel_launch(void* const* d_in, const int* in_sizes, int n_in,
                              void* d_out, int out_size, void* d_ws, size_t ws_size,
                              hipStream_t stream) {
    const float* x  = (const float*)d_in[0];
    const float* Wq = (const float*)d_in[1];
    const float* Wk = (const float*)d_in[2];
    const float* Wv = (const float*)d_in[3];
    const float* Wo = (const float*)d_in[4];
    float* out = (float*)d_out;
    float* attn = out + (size_t)NSEQ * DMODEL;

    char* w = (char*)d_ws;
    auto alloc = [&](size_t bytes) { char* p = w; w += (bytes + 255) & ~(size_t)255; return p; };
    const size_t MD = (size_t)NSEQ * DMODEL;        // 4M elems
    const size_t MKV = (size_t)NSEQ * NKV * DK;     // 1M elems
    _Float16* xh    = (_Float16*)alloc(MD * 2);
    _Float16* WqkvT = (_Float16*)alloc((size_t)3072 * 2048 * 2);
    _Float16* WoT   = (_Float16*)alloc(MD * 2);
    float2*   cs    = (float2*)alloc((size_t)NSEQ * 32 * sizeof(float2));
    _Float16* QKV   = (_Float16*)alloc((size_t)2048 * 3072 * 2);
    _Float16* Kh    = (_Float16*)alloc(MKV * 2);
    _Float16* Vt    = (_Float16*)alloc(MKV * 2);
    _Float16* AVh   = xh;   // reuse (xh dead after QKV projection)

    cvt_f32_f16<<<2048, 256, 0, stream>>>(x, xh, (int)(MD / 4));
    transpose_cvt<<<dim3(64, 64), dim3(32, 8), 0, stream>>>(Wq, WqkvT, DMODEL, DMODEL);
    transpose_cvt<<<dim3(16, 64), dim3(32, 8), 0, stream>>>(Wk, WqkvT + (size_t)2048 * 2048, DMODEL, 512);
    transpose_cvt<<<dim3(16, 64), dim3(32, 8), 0, stream>>>(Wv, WqkvT + (size_t)2560 * 2048, DMODEL, 512);
    transpose_cvt<<<dim3(64, 64), dim3(32, 8), 0, stream>>>(Wo, WoT, DMODEL, DMODEL);
    rope_table<<<256, 256, 0, stream>>>(cs);

    // fused QKV projection: [2048][2048] @ [3072][2048]^T -> [2048][3072]
    gemm_lds<128, 128, 4, 4, _Float16><<<dim3(24, 16), 256, 0, stream>>>(
        xh, WqkvT, QKV, DMODEL, DMODEL, DMODEL, 3072);

    rope_apply16<<<2048, 256, 0, stream>>>(QKV, cs, Kh);
    transpose16p<<<dim3(16, 64), dim3(32, 8), 0, stream>>>(QKV + 2560, Vt, NSEQ, 512, 3072);

    fused_attn<<<dim3(NSEQ / 16, NHEADS), 512, 0, stream>>>(QKV, cs, Kh, Vt, attn, AVh);

    gemm_lds<128, 128, 4, 4, float><<<dim3(16, 16), 256, 0, stream>>>(
        AVh, WoT, out, DMODEL, DMODEL, DMODEL, DMODEL);
}

// Round 11
// 335.080 us; speedup vs baseline: 1.6075x; 1.5442x over previous
//
#include <hip/hip_runtime.h>

typedef _Float16 f16x8 __attribute__((ext_vector_type(8)));
typedef _Float16 f16x4 __attribute__((ext_vector_type(4)));
typedef _Float16 f16x2 __attribute__((ext_vector_type(2)));
typedef float f32x4 __attribute__((ext_vector_type(4)));

#define NSEQ 2048
#define DMODEL 2048
#define NHEADS 32
#define NKV 8
#define DK 64
#define MFMA16(a, b, c) __builtin_amdgcn_mfma_f32_16x16x32_f16(a, b, c, 0, 0, 0)

// async global->LDS, 16B per lane; LDS dest is wave-uniform base + lane*16
__device__ __forceinline__ void gload16(const void* g, void* l) {
    __builtin_amdgcn_global_load_lds(
        (const __attribute__((address_space(1))) void*)g,
        (__attribute__((address_space(3))) void*)l, 16, 0, 0);
}

// ---------------- elementwise f32 -> f16 ----------------
__global__ void cvt_f32_f16(const float* __restrict__ in, _Float16* __restrict__ out, int n4) {
    int i = blockIdx.x * blockDim.x + threadIdx.x;
    int stride = gridDim.x * blockDim.x;
    for (; i < n4; i += stride) {
        float4 v = ((const float4*)in)[i];
        f16x4 h;
        h[0] = (_Float16)v.x; h[1] = (_Float16)v.y;
        h[2] = (_Float16)v.z; h[3] = (_Float16)v.w;
        ((f16x4*)out)[i] = h;
    }
}

// ---------------- transpose + convert: in f32 [R][C] -> out f16 [C][R] ----------------
__global__ __launch_bounds__(256) void transpose_cvt(const float* __restrict__ in,
                                                     _Float16* __restrict__ out,
                                                     int R, int C) {
    __shared__ float tile[32][33];
    int c0 = blockIdx.x * 32, r0 = blockIdx.y * 32;
    int tx = threadIdx.x, ty = threadIdx.y; // (32,8)
#pragma unroll
    for (int i = 0; i < 4; i++) {
        int r = r0 + ty + i * 8;
        tile[ty + i * 8][tx] = in[(long long)r * C + c0 + tx];
    }
    __syncthreads();
#pragma unroll
    for (int i = 0; i < 4; i++) {
        int c = c0 + ty + i * 8;
        out[(long long)c * R + r0 + tx] = (_Float16)tile[tx][ty + i * 8];
    }
}

// ---------------- transpose f16 [R][C] (row pitch) -> f16 [C][R] ----------------
__global__ __launch_bounds__(256) void transpose16p(const _Float16* __restrict__ in,
                                                    _Float16* __restrict__ out,
                                                    int R, int C, int pitch) {
    __shared__ _Float16 tile[32][34];
    int c0 = blockIdx.x * 32, r0 = blockIdx.y * 32;
    int tx = threadIdx.x, ty = threadIdx.y; // (32,8)
#pragma unroll
    for (int i = 0; i < 4; i++) {
        int r = r0 + ty + i * 8;
        tile[ty + i * 8][tx] = in[(long long)r * pitch + c0 + tx];
    }
    __syncthreads();
#pragma unroll
    for (int i = 0; i < 4; i++) {
        int c = c0 + ty + i * 8;
        out[(long long)c * R + r0 + tx] = tile[tx][ty + i * 8];
    }
}

// ---------------- RoPE cos/sin table ----------------
__global__ void rope_table(float2* __restrict__ cs) {
    int idx = blockIdx.x * blockDim.x + threadIdx.x; // 65536 total
    int n = idx >> 5, j = idx & 31;
    float e = (2.0f * j) / 64.0f;
    float invf = 1.0f / powf(10000.0f, e);
    float ang = (float)n * invf;
    float2 v; v.x = cosf(ang); v.y = sinf(ang);
    cs[idx] = v;
}

// ---------------- RoPE apply for K: reads K cols of QKV [2048][3072], writes Kh [2048][512] --
__global__ void rope_apply16(const _Float16* __restrict__ QKV, const float2* __restrict__ cs,
                             _Float16* __restrict__ out) {
    int idx = blockIdx.x * blockDim.x + threadIdx.x; // 2048*256
    int n = idx >> 8, rem = idx & 255;
    int hk = rem >> 5, j = rem & 31;
    float2 c = cs[n * 32 + j];
    const _Float16* in = QKV + (long long)n * 3072 + 2048 + hk * 64;
    float x1 = (float)in[j], x2 = (float)in[j + 32];
    long long ob = (long long)n * 512 + hk * 64;
    out[ob + j]      = (_Float16)(x1 * c.x - x2 * c.y);
    out[ob + j + 32] = (_Float16)(x2 * c.x + x1 * c.y);
}

// ---------------- GEMM (m97 structure): C[M,N] = A[M,K] @ Bt[N,K]^T ----------------
template <int BM, int BN, int MF, int NF, typename OutT>
__global__ __launch_bounds__(256) void gemm_lds(const _Float16* __restrict__ Ap,
                                                const _Float16* __restrict__ Bt,
                                                OutT* __restrict__ C,
                                                int K, int lda, int ldb, int ldc) {
    __shared__ __align__(16) _Float16 As[BM * 32];
    __shared__ __align__(16) _Float16 Bs[BN * 32];

    const int tid = threadIdx.x;
    const int lane = tid & 63, w = tid >> 6;
    constexpr int WC = BN / (NF * 16);
    const int wr = w / WC, wc = w % WC;
    const int wm = wr * MF * 16, wn = wc * NF * 16;
    const int am = lane & 15;
    const int g = lane >> 4;

    f32x4 acc[MF][NF] = {};

    const long long a_row0 = (long long)blockIdx.y * BM * lda;
    const long long b_row0 = (long long)blockIdx.x * BN * ldb;

    const int srow = lane >> 2;        // staging: row within 16-row group
    const int scol = (lane & 3) * 8;   // staging: halfs offset within row

    for (int kt = 0; kt < K; kt += 32) {
#pragma unroll
        for (int q = 0; q < BM / 64; q++) {
            const int row = w * (BM / 4) + q * 16 + srow;
            gload16(Ap + a_row0 + (long long)row * lda + kt + scol,
                    &As[w * (BM * 8) + q * 512]);
        }
#pragma unroll
        for (int q = 0; q < BN / 64; q++) {
            const int row = w * (BN / 4) + q * 16 + srow;
            gload16(Bt + b_row0 + (long long)row * ldb + kt + scol,
                    &Bs[w * (BN * 8) + q * 512]);
        }
        __syncthreads();

        f16x8 af[MF], bf[NF];
#pragma unroll
        for (int m = 0; m < MF; m++) af[m] = *(const f16x8*)&As[(wm + m * 16 + am) * 32 + g * 8];
#pragma unroll
        for (int n = 0; n < NF; n++) bf[n] = *(const f16x8*)&Bs[(wn + n * 16 + am) * 32 + g * 8];
#pragma unroll
        for (int m = 0; m < MF; m++)
#pragma unroll
            for (int n = 0; n < NF; n++)
                acc[m][n] = MFMA16(af[m], bf[n], acc[m][n]);
        __syncthreads();
    }

    const int rb = blockIdx.y * BM + wm + (lane >> 4) * 4;
    const int cb = blockIdx.x * BN + wn + am;
#pragma unroll
    for (int m = 0; m < MF; m++)
#pragma unroll
        for (int n = 0; n < NF; n++)
#pragma unroll
            for (int j = 0; j < 4; j++)
                C[(long long)(rb + m * 16 + j) * ldc + cb + n * 16] = (OutT)acc[m][n][j];
}

// ---------------- fused attention v8: 128 Q-rows/block, shared LDS K/V, two-pass ------------
// 512 thr / 8 waves; wave w owns Q-rows [q0 + w*16, +16) over ALL 2048 kcols.
// Pass 1 (16 chunks x 128 kcols): K dbuf + V single-buf staged via gload16 (pre-swizzled
//   source, v7-validated); QK (swapped mfma(K,Q)) -> exp -> wave-private bounce -> PV;
//   lane-local row sums (no cross-wave reduce). 2 barriers/chunk.
// Pass 2 (16 chunks, NO barriers): recompute QK from L2 (identical bits), e*inv -> wave-
//   private ES strip -> 512B-contiguous f32x4 attn stores, streamed (never vmcnt-drained).
// LDS 64 KB -> 2 blocks/CU. K+V read from L2 once per 128 rows (8x less than v5).
__global__ __launch_bounds__(512) void fused_attn(
    const _Float16* __restrict__ QKV,  // [2048][3072], Q = cols 0..2047 (pre-rope)
    const float2*  __restrict__ cs,    // [2048][32]
    const _Float16* __restrict__ Kh,   // [2048][512] roped
    const _Float16* __restrict__ Vt,   // [512][2048]
    float* __restrict__ attn,          // [32][2048][2048]
    _Float16* __restrict__ AVh)        // [2048][2048]
{
    __shared__ __align__(16) char LB[65536];
    // layout: Kbuf[2] @0 (2x16KB), Vbuf @32768 (16KB), bounce @49152+w*2048 (16KB)
    //         pass2: ES @32768+w*4096 (32KB, overlays Vbuf+bounce)

    const int h = blockIdx.y, q0 = blockIdx.x * 128;
    const int kvh = h >> 2;
    const int tid = threadIdx.x, lane = tid & 63, w = tid >> 6;
    const int g = lane >> 4, c = lane & 15;
    const int swz = (c & 7) << 4;

    // ---- Q fragment (B-operand, Q-row = q0 + w*16 + c) + in-register RoPE ----
    const _Float16* qp = QKV + (long long)(q0 + w * 16 + c) * 3072 + h * 64;
    f16x8 q0v = *(const f16x8*)(qp + g * 8);
    f16x8 q1v = *(const f16x8*)(qp + 32 + g * 8);
    const float2* csp = cs + (q0 + w * 16 + c) * 32 + g * 8;
    f16x8 qa, qb_;
#pragma unroll
    for (int e = 0; e < 8; e++) {
        float2 cv = csp[e];
        float x1 = (float)q0v[e], x2 = (float)q1v[e];
        qa[e]  = (_Float16)(x1 * cv.x - x2 * cv.y);
        qb_[e] = (_Float16)(x2 * cv.x + x1 * cv.y);
    }

    const _Float16* Kg = Kh + kvh * 64;
    const _Float16* Vg = Vt + (long long)(kvh * 64) * NSEQ;
    char* bw = LB + 49152 + w * 2048;

    // staging lane constants (v7-validated)
    const int krl = lane >> 3;          // K: row within 8-row group
    const int kcb = (lane & 7) * 16;    // K: col byte
    const int vrl = lane >> 4;          // V: row within 4-row group
    const int vcb = (lane & 15) * 16;   // V: col byte

    // ---- prologue: stage K chunk 0 into buf 0 ----
#pragma unroll
    for (int q = 0; q < 2; q++) {
        int r = w * 16 + q * 8 + krl;
        gload16(Kg + (long long)r * 512 + ((kcb ^ ((r & 7) << 4)) >> 1),
                LB + (w * 16 + q * 8) * 128);
    }
    __syncthreads();

    float l = 0.f;
    f32x4 opv[4] = {};

    // ================= pass 1: sums + PV (K/V from shared LDS) =================
    for (int i = 0; i < 16; i++) {
        const int kc = i * 128;
        const char* kbuf = LB + (i & 1) * 16384;
        char* kstage = LB + ((i & 1) ^ 1) * 16384;
        // stage K(i+1) and V(i)
        {
            const int nkc = ((i + 1) & 15) * 128;
#pragma unroll
            for (int q = 0; q < 2; q++) {
                int r = w * 16 + q * 8 + krl;
                gload16(Kg + (long long)(nkc + r) * 512 + ((kcb ^ ((r & 7) << 4)) >> 1),
                        kstage + (w * 16 + q * 8) * 128);
            }
#pragma unroll
            for (int q = 0; q < 2; q++) {
                int j = w + q * 8;
                int d = j * 4 + vrl;
                gload16(Vg + (long long)d * NSEQ + kc + ((vcb ^ ((d & 7) << 4)) >> 1),
                        LB + 32768 + j * 1024);
            }
        }
        f16x8 pa0[2], pa1[2];
#pragma unroll
        for (int hh = 0; hh < 2; hh++) {
            // QK: 4 tiles of 16 kcols -> bounce strip (wave-private 16x64)
#pragma unroll
            for (int t4 = 0; t4 < 4; t4++) {
                const int t = hh * 4 + t4;
                const char* kb = kbuf + (t * 16 + c) * 128;
                f16x8 kb0 = *(const f16x8*)(kb + ((g * 16) ^ swz));
                f16x8 kb1 = *(const f16x8*)(kb + ((64 + g * 16) ^ swz));
                f32x4 acc = {0.f, 0.f, 0.f, 0.f};
                acc = MFMA16(kb0, qa, acc);
                acc = MFMA16(kb1, qb_, acc);
                float e0 = __expf(fminf(acc[0] * 0.125f, 11.f));
                float e1 = __expf(fminf(acc[1] * 0.125f, 11.f));
                float e2 = __expf(fminf(acc[2] * 0.125f, 11.f));
                float e3 = __expf(fminf(acc[3] * 0.125f, 11.f));
                l += (e0 + e1) + (e2 + e3);
                f16x2 p01; p01[0] = (_Float16)e0; p01[1] = (_Float16)e1;
                f16x2 p23; p23[0] = (_Float16)e2; p23[1] = (_Float16)e3;
                int b0 = c * 128 + ((t4 * 32 + g * 8) ^ swz);
                *(f16x2*)(bw + b0) = p01;
                *(f16x2*)(bw + b0 + 4) = p23;
            }
            __asm__ volatile("s_waitcnt lgkmcnt(0)" ::: "memory");
            pa0[hh] = *(const f16x8*)(bw + c * 128 + ((g * 16) ^ swz));
            pa1[hh] = *(const f16x8*)(bw + c * 128 + ((64 + g * 16) ^ swz));
            __asm__ volatile("s_waitcnt lgkmcnt(0)" ::: "memory");
            if (hh == 0) __syncthreads();  // V(i) + K(i+1) landed; Kbuf[buf] still valid
            // PV for this 64-col half (V from shared Vbuf)
#pragma unroll
            for (int dt = 0; dt < 4; dt++) {
                const char* vrow = LB + 32768 + (dt * 16 + c) * 256;
                int col0 = hh * 64 + g * 8;
                f16x8 vb0 = *(const f16x8*)(vrow + ((col0 * 2) ^ swz));
                f16x8 vb1 = *(const f16x8*)(vrow + (((col0 + 32) * 2) ^ swz));
                opv[dt] = MFMA16(pa0[hh], vb0, opv[dt]);
                opv[dt] = MFMA16(pa1[hh], vb1, opv[dt]);
            }
        }
        __syncthreads();  // all Vbuf reads done -> free for next stage
    }

    // ---- row sums (lane-local rows!): reduce over g-groups only ----
    l += __shfl_xor(l, 16, 64);
    l += __shfl_xor(l, 32, 64);
    const float inv = 1.0f / l;  // row (q0 + w*16 + c)

    // ---- AV epilogue: O rows 4g+j, d = dt*16+c ----
    float invr[4];
#pragma unroll
    for (int j = 0; j < 4; j++) invr[j] = __shfl(inv, 4 * g + j, 64);
#pragma unroll
    for (int dt = 0; dt < 4; dt++)
#pragma unroll
        for (int j = 0; j < 4; j++)
            AVh[(long long)(q0 + w * 16 + 4 * g + j) * DMODEL + h * 64 + dt * 16 + c] =
                (_Float16)(opv[dt][j] * invr[j]);

    __syncthreads();  // protect ES overlay of Vbuf/bounce

    // ================= pass 2: recompute + streamed contiguous stores (no barriers) =========
    char* ES = LB + 32768 + w * 4096;  // wave-private 16 rows x 256B
    float* arow0 = attn + ((long long)h * NSEQ + q0 + w * 16) * NSEQ;
    for (int ch = 0; ch < 16; ch++) {
        const int kc = ch * 128;
#pragma unroll
        for (int t = 0; t < 8; t++) {
            const _Float16* kp = Kg + (long long)(kc + t * 16 + c) * 512;
            f16x8 kb0 = *(const f16x8*)(kp + g * 8);
            f16x8 kb1 = *(const f16x8*)(kp + 32 + g * 8);
            f32x4 acc = {0.f, 0.f, 0.f, 0.f};
            acc = MFMA16(kb0, qa, acc);
            acc = MFMA16(kb1, qb_, acc);
            float e0 = __expf(fminf(acc[0] * 0.125f, 11.f)) * inv;
            float e1 = __expf(fminf(acc[1] * 0.125f, 11.f)) * inv;
            float e2 = __expf(fminf(acc[2] * 0.125f, 11.f)) * inv;
            float e3 = __expf(fminf(acc[3] * 0.125f, 11.f)) * inv;
            f16x2 p01; p01[0] = (_Float16)e0; p01[1] = (_Float16)e1;
            f16x2 p23; p23[0] = (_Float16)e2; p23[1] = (_Float16)e3;
            int b0 = c * 256 + ((t * 32 + g * 8) ^ swz);
            *(f16x2*)(ES + b0) = p01;
            *(f16x2*)(ES + b0 + 4) = p23;
        }
        __asm__ volatile("s_waitcnt lgkmcnt(0)" ::: "memory");
        // stores: 8 instrs, each 2 rows x 512B contiguous
#pragma unroll
        for (int rr = 0; rr < 8; rr++) {
            const int r = 2 * rr + (lane >> 5);
            f16x4 ev = *(const f16x4*)(ES + r * 256 + (((lane & 31) * 8) ^ ((r & 7) << 4)));
            f32x4 o;
            o[0] = (float)ev[0]; o[1] = (float)ev[1];
            o[2] = (float)ev[2]; o[3] = (float)ev[3];
            *(f32x4*)(arow0 + (long long)r * NSEQ + kc + (lane & 31) * 4) = o;
        }
        __asm__ volatile("s_waitcnt lgkmcnt(0)" ::: "memory");  // ES reads done before overwrite
    }
}

extern "C" void kernel_launch(void* const* d_in, const int* in_sizes, int n_in,
                              void* d_out, int out_size, void* d_ws, size_t ws_size,
                              hipStream_t stream) {
    const float* x  = (const float*)d_in[0];
    const float* Wq = (const float*)d_in[1];
    const float* Wk = (const float*)d_in[2];
    const float* Wv = (const float*)d_in[3];
    const float* Wo = (const float*)d_in[4];
    float* out = (float*)d_out;
    float* attn = out + (size_t)NSEQ * DMODEL;

    char* w = (char*)d_ws;
    auto alloc = [&](size_t bytes) { char* p = w; w += (bytes + 255) & ~(size_t)255; return p; };
    const size_t MD = (size_t)NSEQ * DMODEL;        // 4M elems
    const size_t MKV = (size_t)NSEQ * NKV * DK;     // 1M elems
    _Float16* xh    = (_Float16*)alloc(MD * 2);
    _Float16* WqkvT = (_Float16*)alloc((size_t)3072 * 2048 * 2);
    _Float16* WoT   = (_Float16*)alloc(MD * 2);
    float2*   cs    = (float2*)alloc((size_t)NSEQ * 32 * sizeof(float2));
    _Float16* QKV   = (_Float16*)alloc((size_t)2048 * 3072 * 2);
    _Float16* Kh    = (_Float16*)alloc(MKV * 2);
    _Float16* Vt    = (_Float16*)alloc(MKV * 2);
    _Float16* AVh   = xh;   // reuse (xh dead after QKV projection)

    cvt_f32_f16<<<2048, 256, 0, stream>>>(x, xh, (int)(MD / 4));
    transpose_cvt<<<dim3(64, 64), dim3(32, 8), 0, stream>>>(Wq, WqkvT, DMODEL, DMODEL);
    transpose_cvt<<<dim3(16, 64), dim3(32, 8), 0, stream>>>(Wk, WqkvT + (size_t)2048 * 2048, DMODEL, 512);
    transpose_cvt<<<dim3(16, 64), dim3(32, 8), 0, stream>>>(Wv, WqkvT + (size_t)2560 * 2048, DMODEL, 512);
    transpose_cvt<<<dim3(64, 64), dim3(32, 8), 0, stream>>>(Wo, WoT, DMODEL, DMODEL);
    rope_table<<<256, 256, 0, stream>>>(cs);

    // fused QKV projection: [2048][2048] @ [3072][2048]^T -> [2048][3072]
    gemm_lds<128, 128, 4, 4, _Float16><<<dim3(24, 16), 256, 0, stream>>>(
        xh, WqkvT, QKV, DMODEL, DMODEL, DMODEL, 3072);

    rope_apply16<<<2048, 256, 0, stream>>>(QKV, cs, Kh);
    transpose16p<<<dim3(16, 64), dim3(32, 8), 0, stream>>>(QKV + 2560, Vt, NSEQ, 512, 3072);

    fused_attn<<<dim3(NSEQ / 128, NHEADS), 512, 0, stream>>>(QKV, cs, Kh, Vt, attn, AVh);

    gemm_lds<128, 128, 4, 4, float><<<dim3(16, 16), 256, 0, stream>>>(
        AVh, WoT, out, DMODEL, DMODEL, DMODEL, DMODEL);
}

// Round 12
// 302.746 us; speedup vs baseline: 1.7792x; 1.1068x over previous
//
#include <hip/hip_runtime.h>

typedef _Float16 f16x8 __attribute__((ext_vector_type(8)));
typedef _Float16 f16x4 __attribute__((ext_vector_type(4)));
typedef _Float16 f16x2 __attribute__((ext_vector_type(2)));
typedef float f32x4 __attribute__((ext_vector_type(4)));

#define NSEQ 2048
#define DMODEL 2048
#define NHEADS 32
#define NKV 8
#define DK 64
#define MFMA16(a, b, c) __builtin_amdgcn_mfma_f32_16x16x32_f16(a, b, c, 0, 0, 0)

// async global->LDS, 16B per lane; LDS dest is wave-uniform base + lane*16
__device__ __forceinline__ void gload16(const void* g, void* l) {
    __builtin_amdgcn_global_load_lds(
        (const __attribute__((address_space(1))) void*)g,
        (__attribute__((address_space(3))) void*)l, 16, 0, 0);
}

// ---------------- elementwise f32 -> f16 ----------------
__global__ void cvt_f32_f16(const float* __restrict__ in, _Float16* __restrict__ out, int n4) {
    int i = blockIdx.x * blockDim.x + threadIdx.x;
    int stride = gridDim.x * blockDim.x;
    for (; i < n4; i += stride) {
        float4 v = ((const float4*)in)[i];
        f16x4 h;
        h[0] = (_Float16)v.x; h[1] = (_Float16)v.y;
        h[2] = (_Float16)v.z; h[3] = (_Float16)v.w;
        ((f16x4*)out)[i] = h;
    }
}

// ---------------- transpose + convert: in f32 [R][C] -> out f16 [C][R] ----------------
__global__ __launch_bounds__(256) void transpose_cvt(const float* __restrict__ in,
                                                     _Float16* __restrict__ out,
                                                     int R, int C) {
    __shared__ float tile[32][33];
    int c0 = blockIdx.x * 32, r0 = blockIdx.y * 32;
    int tx = threadIdx.x, ty = threadIdx.y; // (32,8)
#pragma unroll
    for (int i = 0; i < 4; i++) {
        int r = r0 + ty + i * 8;
        tile[ty + i * 8][tx] = in[(long long)r * C + c0 + tx];
    }
    __syncthreads();
#pragma unroll
    for (int i = 0; i < 4; i++) {
        int c = c0 + ty + i * 8;
        out[(long long)c * R + r0 + tx] = (_Float16)tile[tx][ty + i * 8];
    }
}

// ---------------- transpose f16 [R][C] (row pitch) -> f16 [C][R] ----------------
__global__ __launch_bounds__(256) void transpose16p(const _Float16* __restrict__ in,
                                                    _Float16* __restrict__ out,
                                                    int R, int C, int pitch) {
    __shared__ _Float16 tile[32][34];
    int c0 = blockIdx.x * 32, r0 = blockIdx.y * 32;
    int tx = threadIdx.x, ty = threadIdx.y; // (32,8)
#pragma unroll
    for (int i = 0; i < 4; i++) {
        int r = r0 + ty + i * 8;
        tile[ty + i * 8][tx] = in[(long long)r * pitch + c0 + tx];
    }
    __syncthreads();
#pragma unroll
    for (int i = 0; i < 4; i++) {
        int c = c0 + ty + i * 8;
        out[(long long)c * R + r0 + tx] = tile[tx][ty + i * 8];
    }
}

// ---------------- RoPE cos/sin table ----------------
__global__ void rope_table(float2* __restrict__ cs) {
    int idx = blockIdx.x * blockDim.x + threadIdx.x; // 65536 total
    int n = idx >> 5, j = idx & 31;
    float e = (2.0f * j) / 64.0f;
    float invf = 1.0f / powf(10000.0f, e);
    float ang = (float)n * invf;
    float2 v; v.x = cosf(ang); v.y = sinf(ang);
    cs[idx] = v;
}

// ---------------- RoPE apply for K: reads K cols of QKV [2048][3072], writes Kh [2048][512] --
__global__ void rope_apply16(const _Float16* __restrict__ QKV, const float2* __restrict__ cs,
                             _Float16* __restrict__ out) {
    int idx = blockIdx.x * blockDim.x + threadIdx.x; // 2048*256
    int n = idx >> 8, rem = idx & 255;
    int hk = rem >> 5, j = rem & 31;
    float2 c = cs[n * 32 + j];
    const _Float16* in = QKV + (long long)n * 3072 + 2048 + hk * 64;
    float x1 = (float)in[j], x2 = (float)in[j + 32];
    long long ob = (long long)n * 512 + hk * 64;
    out[ob + j]      = (_Float16)(x1 * c.x - x2 * c.y);
    out[ob + j + 32] = (_Float16)(x2 * c.x + x1 * c.y);
}

// ---------------- GEMM (m97 structure): C[M,N] = A[M,K] @ Bt[N,K]^T ----------------
template <int BM, int BN, int MF, int NF, typename OutT>
__global__ __launch_bounds__(256) void gemm_lds(const _Float16* __restrict__ Ap,
                                                const _Float16* __restrict__ Bt,
                                                OutT* __restrict__ C,
                                                int K, int lda, int ldb, int ldc) {
    __shared__ __align__(16) _Float16 As[BM * 32];
    __shared__ __align__(16) _Float16 Bs[BN * 32];

    const int tid = threadIdx.x;
    const int lane = tid & 63, w = tid >> 6;
    constexpr int WC = BN / (NF * 16);
    const int wr = w / WC, wc = w % WC;
    const int wm = wr * MF * 16, wn = wc * NF * 16;
    const int am = lane & 15;
    const int g = lane >> 4;

    f32x4 acc[MF][NF] = {};

    const long long a_row0 = (long long)blockIdx.y * BM * lda;
    const long long b_row0 = (long long)blockIdx.x * BN * ldb;

    const int srow = lane >> 2;        // staging: row within 16-row group
    const int scol = (lane & 3) * 8;   // staging: halfs offset within row

    for (int kt = 0; kt < K; kt += 32) {
#pragma unroll
        for (int q = 0; q < BM / 64; q++) {
            const int row = w * (BM / 4) + q * 16 + srow;
            gload16(Ap + a_row0 + (long long)row * lda + kt + scol,
                    &As[w * (BM * 8) + q * 512]);
        }
#pragma unroll
        for (int q = 0; q < BN / 64; q++) {
            const int row = w * (BN / 4) + q * 16 + srow;
            gload16(Bt + b_row0 + (long long)row * ldb + kt + scol,
                    &Bs[w * (BN * 8) + q * 512]);
        }
        __syncthreads();

        f16x8 af[MF], bf[NF];
#pragma unroll
        for (int m = 0; m < MF; m++) af[m] = *(const f16x8*)&As[(wm + m * 16 + am) * 32 + g * 8];
#pragma unroll
        for (int n = 0; n < NF; n++) bf[n] = *(const f16x8*)&Bs[(wn + n * 16 + am) * 32 + g * 8];
#pragma unroll
        for (int m = 0; m < MF; m++)
#pragma unroll
            for (int n = 0; n < NF; n++)
                acc[m][n] = MFMA16(af[m], bf[n], acc[m][n]);
        __syncthreads();
    }

    const int rb = blockIdx.y * BM + wm + (lane >> 4) * 4;
    const int cb = blockIdx.x * BN + wn + am;
#pragma unroll
    for (int m = 0; m < MF; m++)
#pragma unroll
        for (int n = 0; n < NF; n++)
#pragma unroll
            for (int j = 0; j < 4; j++)
                C[(long long)(rb + m * 16 + j) * ldc + cb + n * 16] = (OutT)acc[m][n][j];
}

// ---------------- kernel A: row sums -> Sinv[32][2048] ----------------
// v8 pass-1 skeleton minus PV/E: K dbuf staged (identical bytes/ops as fused_attn =>
// bitwise-identical e), lane-local sums, 1 barrier/chunk. Grid (16, 32), 32 KB LDS.
__global__ __launch_bounds__(512) void attn_sums(
    const _Float16* __restrict__ QKV,  // [2048][3072] (Q cols 0..2047, pre-rope)
    const float2*  __restrict__ cs,    // [2048][32]
    const _Float16* __restrict__ Kh,   // [2048][512] roped
    float* __restrict__ Sinv)          // [32][2048]
{
    __shared__ __align__(16) char LB[32768]; // Kbuf[2] 2x16KB

    const int h = blockIdx.y, q0 = blockIdx.x * 128;
    const int kvh = h >> 2;
    const int tid = threadIdx.x, lane = tid & 63, w = tid >> 6;
    const int g = lane >> 4, c = lane & 15;
    const int swz = (c & 7) << 4;

    const _Float16* qp = QKV + (long long)(q0 + w * 16 + c) * 3072 + h * 64;
    f16x8 q0v = *(const f16x8*)(qp + g * 8);
    f16x8 q1v = *(const f16x8*)(qp + 32 + g * 8);
    const float2* csp = cs + (q0 + w * 16 + c) * 32 + g * 8;
    f16x8 qa, qb_;
#pragma unroll
    for (int e = 0; e < 8; e++) {
        float2 cv = csp[e];
        float x1 = (float)q0v[e], x2 = (float)q1v[e];
        qa[e]  = (_Float16)(x1 * cv.x - x2 * cv.y);
        qb_[e] = (_Float16)(x2 * cv.x + x1 * cv.y);
    }

    const _Float16* Kg = Kh + kvh * 64;
    const int krl = lane >> 3, kcb = (lane & 7) * 16;

#pragma unroll
    for (int q = 0; q < 2; q++) {
        int r = w * 16 + q * 8 + krl;
        gload16(Kg + (long long)r * 512 + ((kcb ^ ((r & 7) << 4)) >> 1),
                LB + (w * 16 + q * 8) * 128);
    }
    __syncthreads();

    float l = 0.f;
    for (int i = 0; i < 16; i++) {
        const char* kbuf = LB + (i & 1) * 16384;
        char* kstage = LB + ((i & 1) ^ 1) * 16384;
        const int nkc = ((i + 1) & 15) * 128;
#pragma unroll
        for (int q = 0; q < 2; q++) {
            int r = w * 16 + q * 8 + krl;
            gload16(Kg + (long long)(nkc + r) * 512 + ((kcb ^ ((r & 7) << 4)) >> 1),
                    kstage + (w * 16 + q * 8) * 128);
        }
#pragma unroll
        for (int t = 0; t < 8; t++) {
            const char* kb = kbuf + (t * 16 + c) * 128;
            f16x8 kb0 = *(const f16x8*)(kb + ((g * 16) ^ swz));
            f16x8 kb1 = *(const f16x8*)(kb + ((64 + g * 16) ^ swz));
            f32x4 acc = {0.f, 0.f, 0.f, 0.f};
            acc = MFMA16(kb0, qa, acc);
            acc = MFMA16(kb1, qb_, acc);
            l += __expf(fminf(acc[0] * 0.125f, 11.f)) + __expf(fminf(acc[1] * 0.125f, 11.f)) +
                 __expf(fminf(acc[2] * 0.125f, 11.f)) + __expf(fminf(acc[3] * 0.125f, 11.f));
        }
        __syncthreads();
    }
    l += __shfl_xor(l, 16, 64);
    l += __shfl_xor(l, 32, 64);
    if (lane < 16)
        Sinv[(long long)h * NSEQ + q0 + w * 16 + c] = 1.0f / l;
}

// ---------------- fused attention v9: single pass, precomputed Sinv ----------------
// 512 thr / 8 waves; wave w owns Q-rows [q0 + w*16, +16) over ALL 2048 kcols.
// Per 128-kcol chunk: stage K(next) dbuf + V(cur); QK from LDS -> p = e*inv (f16) ->
// wave-private ES strip (16 x 256B, swizzled) -> PV A-frags + 512B-contiguous f32x4
// attn stores from the same strip. 2 barriers/chunk. No reductions, no recompute.
// LDS: Kbuf 32K @0, Vbuf 16K @32768, ES 32K @49152 = 80 KB -> 2 blocks/CU (exact fit).
__global__ __launch_bounds__(512) void fused_attn(
    const _Float16* __restrict__ QKV,  // [2048][3072], Q = cols 0..2047 (pre-rope)
    const float2*  __restrict__ cs,    // [2048][32]
    const _Float16* __restrict__ Kh,   // [2048][512] roped
    const _Float16* __restrict__ Vt,   // [512][2048]
    const float* __restrict__ Sinv,    // [32][2048]
    float* __restrict__ attn,          // [32][2048][2048]
    _Float16* __restrict__ AVh)        // [2048][2048]
{
    __shared__ __align__(16) char LB[81920];

    const int h = blockIdx.y, q0 = blockIdx.x * 128;
    const int kvh = h >> 2;
    const int tid = threadIdx.x, lane = tid & 63, w = tid >> 6;
    const int g = lane >> 4, c = lane & 15;
    const int swz = (c & 7) << 4;

    // ---- Q fragment + in-register RoPE ----
    const _Float16* qp = QKV + (long long)(q0 + w * 16 + c) * 3072 + h * 64;
    f16x8 q0v = *(const f16x8*)(qp + g * 8);
    f16x8 q1v = *(const f16x8*)(qp + 32 + g * 8);
    const float2* csp = cs + (q0 + w * 16 + c) * 32 + g * 8;
    f16x8 qa, qb_;
#pragma unroll
    for (int e = 0; e < 8; e++) {
        float2 cv = csp[e];
        float x1 = (float)q0v[e], x2 = (float)q1v[e];
        qa[e]  = (_Float16)(x1 * cv.x - x2 * cv.y);
        qb_[e] = (_Float16)(x2 * cv.x + x1 * cv.y);
    }

    const float inv = Sinv[(long long)h * NSEQ + q0 + w * 16 + c];

    const _Float16* Kg = Kh + kvh * 64;
    const _Float16* Vg = Vt + (long long)(kvh * 64) * NSEQ;
    char* ES = LB + 49152 + w * 4096;  // 16 rows x 256B, wave-private
    float* arow0 = attn + ((long long)h * NSEQ + q0 + w * 16) * NSEQ;

    const int krl = lane >> 3, kcb = (lane & 7) * 16;
    const int vrl = lane >> 4, vcb = (lane & 15) * 16;

    // ---- prologue: stage K chunk 0 into buf 0 ----
#pragma unroll
    for (int q = 0; q < 2; q++) {
        int r = w * 16 + q * 8 + krl;
        gload16(Kg + (long long)r * 512 + ((kcb ^ ((r & 7) << 4)) >> 1),
                LB + (w * 16 + q * 8) * 128);
    }
    __syncthreads();

    f32x4 opv[4] = {};

    for (int i = 0; i < 16; i++) {
        const int kc = i * 128;
        const char* kbuf = LB + (i & 1) * 16384;
        char* kstage = LB + ((i & 1) ^ 1) * 16384;
        const int nkc = ((i + 1) & 15) * 128;
        // stage K(i+1) and V(i)
#pragma unroll
        for (int q = 0; q < 2; q++) {
            int r = w * 16 + q * 8 + krl;
            gload16(Kg + (long long)(nkc + r) * 512 + ((kcb ^ ((r & 7) << 4)) >> 1),
                    kstage + (w * 16 + q * 8) * 128);
        }
#pragma unroll
        for (int q = 0; q < 2; q++) {
            int j = w + q * 8;
            int d = j * 4 + vrl;
            gload16(Vg + (long long)d * NSEQ + kc + ((vcb ^ ((d & 7) << 4)) >> 1),
                    LB + 32768 + j * 1024);
        }
        // ---- hh=0: QK tiles 0-3 -> p -> ES bytes [0,128) ----
#pragma unroll
        for (int t = 0; t < 4; t++) {
            const char* kb = kbuf + (t * 16 + c) * 128;
            f16x8 kb0 = *(const f16x8*)(kb + ((g * 16) ^ swz));
            f16x8 kb1 = *(const f16x8*)(kb + ((64 + g * 16) ^ swz));
            f32x4 acc = {0.f, 0.f, 0.f, 0.f};
            acc = MFMA16(kb0, qa, acc);
            acc = MFMA16(kb1, qb_, acc);
            float p0 = __expf(fminf(acc[0] * 0.125f, 11.f)) * inv;
            float p1 = __expf(fminf(acc[1] * 0.125f, 11.f)) * inv;
            float p2 = __expf(fminf(acc[2] * 0.125f, 11.f)) * inv;
            float p3 = __expf(fminf(acc[3] * 0.125f, 11.f)) * inv;
            f16x2 a01; a01[0] = (_Float16)p0; a01[1] = (_Float16)p1;
            f16x2 a23; a23[0] = (_Float16)p2; a23[1] = (_Float16)p3;
            int b0 = c * 256 + ((t * 32 + g * 8) ^ swz);
            *(f16x2*)(ES + b0) = a01;
            *(f16x2*)(ES + b0 + 4) = a23;
        }
        __asm__ volatile("s_waitcnt lgkmcnt(0)" ::: "memory");
        f16x8 pa0 = *(const f16x8*)(ES + c * 256 + ((g * 16) ^ swz));
        f16x8 pa1 = *(const f16x8*)(ES + c * 256 + ((64 + g * 16) ^ swz));
        __syncthreads();  // V(i) + K(i+1) landed
        // PV cols 0-63
#pragma unroll
        for (int dt = 0; dt < 4; dt++) {
            const char* vrow = LB + 32768 + (dt * 16 + c) * 256;
            f16x8 vb0 = *(const f16x8*)(vrow + ((g * 16) ^ swz));
            f16x8 vb1 = *(const f16x8*)(vrow + ((64 + g * 16) ^ swz));
            opv[dt] = MFMA16(pa0, vb0, opv[dt]);
            opv[dt] = MFMA16(pa1, vb1, opv[dt]);
        }
        // ---- hh=1: QK tiles 4-7 -> ES bytes [128,256) ----
#pragma unroll
        for (int t = 4; t < 8; t++) {
            const char* kb = kbuf + (t * 16 + c) * 128;
            f16x8 kb0 = *(const f16x8*)(kb + ((g * 16) ^ swz));
            f16x8 kb1 = *(const f16x8*)(kb + ((64 + g * 16) ^ swz));
            f32x4 acc = {0.f, 0.f, 0.f, 0.f};
            acc = MFMA16(kb0, qa, acc);
            acc = MFMA16(kb1, qb_, acc);
            float p0 = __expf(fminf(acc[0] * 0.125f, 11.f)) * inv;
            float p1 = __expf(fminf(acc[1] * 0.125f, 11.f)) * inv;
            float p2 = __expf(fminf(acc[2] * 0.125f, 11.f)) * inv;
            float p3 = __expf(fminf(acc[3] * 0.125f, 11.f)) * inv;
            f16x2 a01; a01[0] = (_Float16)p0; a01[1] = (_Float16)p1;
            f16x2 a23; a23[0] = (_Float16)p2; a23[1] = (_Float16)p3;
            int b0 = c * 256 + ((t * 32 + g * 8) ^ swz);
            *(f16x2*)(ES + b0) = a01;
            *(f16x2*)(ES + b0 + 4) = a23;
        }
        __asm__ volatile("s_waitcnt lgkmcnt(0)" ::: "memory");
        f16x8 pa2 = *(const f16x8*)(ES + c * 256 + ((128 + g * 16) ^ swz));
        f16x8 pa3 = *(const f16x8*)(ES + c * 256 + ((192 + g * 16) ^ swz));
        // ---- attn stores: 8 instrs, each 2 rows x 512B contiguous ----
#pragma unroll
        for (int rr = 0; rr < 8; rr++) {
            const int r = 2 * rr + (lane >> 5);
            f16x4 ev = *(const f16x4*)(ES + r * 256 + (((lane & 31) * 8) ^ ((r & 7) << 4)));
            f32x4 o;
            o[0] = (float)ev[0]; o[1] = (float)ev[1];
            o[2] = (float)ev[2]; o[3] = (float)ev[3];
            *(f32x4*)(arow0 + (long long)r * NSEQ + kc + (lane & 31) * 4) = o;
        }
        // PV cols 64-127
#pragma unroll
        for (int dt = 0; dt < 4; dt++) {
            const char* vrow = LB + 32768 + (dt * 16 + c) * 256;
            f16x8 vb2 = *(const f16x8*)(vrow + ((128 + g * 16) ^ swz));
            f16x8 vb3 = *(const f16x8*)(vrow + ((192 + g * 16) ^ swz));
            opv[dt] = MFMA16(pa2, vb2, opv[dt]);
            opv[dt] = MFMA16(pa3, vb3, opv[dt]);
        }
        __syncthreads();  // ES/Vbuf/Kbuf reads done; stages drained
    }

    // ---- AV epilogue (p already normalized) ----
#pragma unroll
    for (int dt = 0; dt < 4; dt++)
#pragma unroll
        for (int j = 0; j < 4; j++)
            AVh[(long long)(q0 + w * 16 + 4 * g + j) * DMODEL + h * 64 + dt * 16 + c] =
                (_Float16)opv[dt][j];
}

extern "C" void kernel_launch(void* const* d_in, const int* in_sizes, int n_in,
                              void* d_out, int out_size, void* d_ws, size_t ws_size,
                              hipStream_t stream) {
    const float* x  = (const float*)d_in[0];
    const float* Wq = (const float*)d_in[1];
    const float* Wk = (const float*)d_in[2];
    const float* Wv = (const float*)d_in[3];
    const float* Wo = (const float*)d_in[4];
    float* out = (float*)d_out;
    float* attn = out + (size_t)NSEQ * DMODEL;

    char* w = (char*)d_ws;
    auto alloc = [&](size_t bytes) { char* p = w; w += (bytes + 255) & ~(size_t)255; return p; };
    const size_t MD = (size_t)NSEQ * DMODEL;        // 4M elems
    const size_t MKV = (size_t)NSEQ * NKV * DK;     // 1M elems
    _Float16* xh    = (_Float16*)alloc(MD * 2);
    _Float16* WqkvT = (_Float16*)alloc((size_t)3072 * 2048 * 2);
    _Float16* WoT   = (_Float16*)alloc(MD * 2);
    float2*   cs    = (float2*)alloc((size_t)NSEQ * 32 * sizeof(float2));
    _Float16* QKV   = (_Float16*)alloc((size_t)2048 * 3072 * 2);
    _Float16* Kh    = (_Float16*)alloc(MKV * 2);
    _Float16* Vt    = (_Float16*)alloc(MKV * 2);
    float*    Sinv  = (float*)alloc((size_t)NHEADS * NSEQ * 4);
    _Float16* AVh   = xh;   // reuse (xh dead after QKV projection)

    cvt_f32_f16<<<2048, 256, 0, stream>>>(x, xh, (int)(MD / 4));
    transpose_cvt<<<dim3(64, 64), dim3(32, 8), 0, stream>>>(Wq, WqkvT, DMODEL, DMODEL);
    transpose_cvt<<<dim3(16, 64), dim3(32, 8), 0, stream>>>(Wk, WqkvT + (size_t)2048 * 2048, DMODEL, 512);
    transpose_cvt<<<dim3(16, 64), dim3(32, 8), 0, stream>>>(Wv, WqkvT + (size_t)2560 * 2048, DMODEL, 512);
    transpose_cvt<<<dim3(64, 64), dim3(32, 8), 0, stream>>>(Wo, WoT, DMODEL, DMODEL);
    rope_table<<<256, 256, 0, stream>>>(cs);

    // fused QKV projection: [2048][2048] @ [3072][2048]^T -> [2048][3072]
    gemm_lds<128, 128, 4, 4, _Float16><<<dim3(24, 16), 256, 0, stream>>>(
        xh, WqkvT, QKV, DMODEL, DMODEL, DMODEL, 3072);

    rope_apply16<<<2048, 256, 0, stream>>>(QKV, cs, Kh);
    transpose16p<<<dim3(16, 64), dim3(32, 8), 0, stream>>>(QKV + 2560, Vt, NSEQ, 512, 3072);

    attn_sums<<<dim3(NSEQ / 128, NHEADS), 512, 0, stream>>>(QKV, cs, Kh, Sinv);

    fused_attn<<<dim3(NSEQ / 128, NHEADS), 512, 0, stream>>>(QKV, cs, Kh, Vt, Sinv, attn, AVh);

    gemm_lds<128, 128, 4, 4, float><<<dim3(16, 16), 256, 0, stream>>>(
        AVh, WoT, out, DMODEL, DMODEL, DMODEL, DMODEL);
}

// Round 14
// 264.018 us; speedup vs baseline: 2.0402x; 1.1467x over previous
//
#include <hip/hip_runtime.h>

typedef _Float16 f16x8 __attribute__((ext_vector_type(8)));
typedef _Float16 f16x4 __attribute__((ext_vector_type(4)));
typedef _Float16 f16x2 __attribute__((ext_vector_type(2)));
typedef float f32x4 __attribute__((ext_vector_type(4)));

#define NSEQ 2048
#define DMODEL 2048
#define NHEADS 32
#define NKV 8
#define DK 64
#define MFMA16(a, b, c) __builtin_amdgcn_mfma_f32_16x16x32_f16(a, b, c, 0, 0, 0)

// async global->LDS, 16B per lane; LDS dest is wave-uniform base + lane*16
__device__ __forceinline__ void gload16(const void* g, void* l) {
    __builtin_amdgcn_global_load_lds(
        (const __attribute__((address_space(1))) void*)g,
        (__attribute__((address_space(3))) void*)l, 16, 0, 0);
}

// ---------------- fused prep: x f32->f16 copy + 4 weight transposes ----------------
__global__ __launch_bounds__(256) void prep_weights(
    const float* __restrict__ x,  const float* __restrict__ Wq,
    const float* __restrict__ Wk, const float* __restrict__ Wv,
    const float* __restrict__ Wo, _Float16* __restrict__ xh,
    _Float16* __restrict__ WqkvT, _Float16* __restrict__ WoT) {
    const int z = blockIdx.z;
    const int tx = threadIdx.x, ty = threadIdx.y; // (32,8)
    if (z == 0) {
        int c0 = blockIdx.x * 32, r0 = blockIdx.y * 32;
#pragma unroll
        for (int i = 0; i < 4; i++) {
            int r = r0 + ty + i * 8;
            xh[(long long)r * DMODEL + c0 + tx] = (_Float16)x[(long long)r * DMODEL + c0 + tx];
        }
        return;
    }
    const float* in; _Float16* out; int C;
    if (z == 1)      { in = Wq; out = WqkvT;                        C = 2048; }
    else if (z == 2) { in = Wk; out = WqkvT + (size_t)2048 * 2048;  C = 512;  }
    else if (z == 3) { in = Wv; out = WqkvT + (size_t)2560 * 2048;  C = 512;  }
    else             { in = Wo; out = WoT;                          C = 2048; }
    int c0 = blockIdx.x * 32, r0 = blockIdx.y * 32;
    if (c0 >= C) return;
    __shared__ float tile[32][33];
#pragma unroll
    for (int i = 0; i < 4; i++) {
        int r = r0 + ty + i * 8;
        tile[ty + i * 8][tx] = in[(long long)r * C + c0 + tx];
    }
    __syncthreads();
#pragma unroll
    for (int i = 0; i < 4; i++) {
        int c = c0 + ty + i * 8;
        out[(long long)c * 2048 + r0 + tx] = (_Float16)tile[tx][ty + i * 8];
    }
}

// ---------------- transpose f16 [R][C] (row pitch) -> f16 [C][R] ----------------
__global__ __launch_bounds__(256) void transpose16p(const _Float16* __restrict__ in,
                                                    _Float16* __restrict__ out,
                                                    int R, int C, int pitch) {
    __shared__ _Float16 tile[32][34];
    int c0 = blockIdx.x * 32, r0 = blockIdx.y * 32;
    int tx = threadIdx.x, ty = threadIdx.y; // (32,8)
#pragma unroll
    for (int i = 0; i < 4; i++) {
        int r = r0 + ty + i * 8;
        tile[ty + i * 8][tx] = in[(long long)r * pitch + c0 + tx];
    }
    __syncthreads();
#pragma unroll
    for (int i = 0; i < 4; i++) {
        int c = c0 + ty + i * 8;
        out[(long long)c * R + r0 + tx] = tile[tx][ty + i * 8];
    }
}

// ---------------- RoPE cos/sin table ----------------
__global__ void rope_table(float2* __restrict__ cs) {
    int idx = blockIdx.x * blockDim.x + threadIdx.x; // 65536 total
    int n = idx >> 5, j = idx & 31;
    float e = (2.0f * j) / 64.0f;
    float invf = 1.0f / powf(10000.0f, e);
    float ang = (float)n * invf;
    float2 v; v.x = cosf(ang); v.y = sinf(ang);
    cs[idx] = v;
}

// ---------------- RoPE apply for K: reads K cols of QKV [2048][3072], writes Kh [2048][512] --
__global__ void rope_apply16(const _Float16* __restrict__ QKV, const float2* __restrict__ cs,
                             _Float16* __restrict__ out) {
    int idx = blockIdx.x * blockDim.x + threadIdx.x; // 2048*256
    int n = idx >> 8, rem = idx & 255;
    int hk = rem >> 5, j = rem & 31;
    float2 c = cs[n * 32 + j];
    const _Float16* in = QKV + (long long)n * 3072 + 2048 + hk * 64;
    float x1 = (float)in[j], x2 = (float)in[j + 32];
    long long ob = (long long)n * 512 + hk * 64;
    out[ob + j]      = (_Float16)(x1 * c.x - x2 * c.y);
    out[ob + j + 32] = (_Float16)(x2 * c.x + x1 * c.y);
}

// ---------------- GEMM v2: BK=64, XOR-swizzled LDS rows, C[M,N] = A @ Bt^T ----------------
// Staging: gload16 with PRE-SWIZZLED global source (byte col ^ (row&7)<<4), linear LDS dest.
// Read: byte (ks*64 + g*16) ^ ((row&7)<<4)  [FIXED: was ks*128 -> read past the 128B row].
template <int BM, int BN, int MF, int NF, typename OutT>
__global__ __launch_bounds__(256) void gemm_lds2(const _Float16* __restrict__ Ap,
                                                 const _Float16* __restrict__ Bt,
                                                 OutT* __restrict__ C,
                                                 int K, int lda, int ldb, int ldc) {
    __shared__ __align__(16) _Float16 As[BM * 64];
    __shared__ __align__(16) _Float16 Bs[BN * 64];

    const int tid = threadIdx.x;
    const int lane = tid & 63, w = tid >> 6;
    constexpr int WC = BN / (NF * 16);
    const int wr = w / WC, wc = w % WC;
    const int wm = wr * MF * 16, wn = wc * NF * 16;
    const int am = lane & 15;
    const int g = lane >> 4;
    const int aswz = (am & 7) << 4;

    f32x4 acc[MF][NF] = {};

    const long long a_row0 = (long long)blockIdx.y * BM * lda;
    const long long b_row0 = (long long)blockIdx.x * BN * ldb;

    const int srow = lane >> 3;        // staging: row within 8-row group
    const int scolb = (lane & 7) * 16; // staging: byte col within 128B row

    for (int kt = 0; kt < K; kt += 64) {
#pragma unroll
        for (int q = 0; q < BM / 32; q++) {
            const int rA = w * (BM / 4) + q * 8;
            const int r = rA + srow;
            gload16(Ap + a_row0 + (long long)r * lda + kt + ((scolb ^ ((r & 7) << 4)) >> 1),
                    &As[rA * 64]);
        }
#pragma unroll
        for (int q = 0; q < BN / 32; q++) {
            const int rB = w * (BN / 4) + q * 8;
            const int r = rB + srow;
            gload16(Bt + b_row0 + (long long)r * ldb + kt + ((scolb ^ ((r & 7) << 4)) >> 1),
                    &Bs[rB * 64]);
        }
        __syncthreads();

#pragma unroll
        for (int ks = 0; ks < 2; ks++) {
            const int koff = ((ks * 64 + g * 16) ^ aswz) >> 1; // byte->half (FIXED)
            f16x8 af[MF], bf[NF];
#pragma unroll
            for (int m = 0; m < MF; m++)
                af[m] = *(const f16x8*)&As[(wm + m * 16 + am) * 64 + koff];
#pragma unroll
            for (int n = 0; n < NF; n++)
                bf[n] = *(const f16x8*)&Bs[(wn + n * 16 + am) * 64 + koff];
#pragma unroll
            for (int m = 0; m < MF; m++)
#pragma unroll
                for (int n = 0; n < NF; n++)
                    acc[m][n] = MFMA16(af[m], bf[n], acc[m][n]);
        }
        __syncthreads();
    }

    const int rb = blockIdx.y * BM + wm + (lane >> 4) * 4;
    const int cb = blockIdx.x * BN + wn + am;
#pragma unroll
    for (int m = 0; m < MF; m++)
#pragma unroll
        for (int n = 0; n < NF; n++)
#pragma unroll
            for (int j = 0; j < 4; j++)
                C[(long long)(rb + m * 16 + j) * ldc + cb + n * 16] = (OutT)acc[m][n][j];
}

// ---------------- kernel A: row sums -> Sinv[32][2048] (unchanged) ----------------
__global__ __launch_bounds__(512) void attn_sums(
    const _Float16* __restrict__ QKV,  // [2048][3072] (Q cols 0..2047, pre-rope)
    const float2*  __restrict__ cs,    // [2048][32]
    const _Float16* __restrict__ Kh,   // [2048][512] roped
    float* __restrict__ Sinv)          // [32][2048]
{
    __shared__ __align__(16) char LB[32768]; // Kbuf[2] 2x16KB

    const int h = blockIdx.y, q0 = blockIdx.x * 128;
    const int kvh = h >> 2;
    const int tid = threadIdx.x, lane = tid & 63, w = tid >> 6;
    const int g = lane >> 4, c = lane & 15;
    const int swz = (c & 7) << 4;

    const _Float16* qp = QKV + (long long)(q0 + w * 16 + c) * 3072 + h * 64;
    f16x8 q0v = *(const f16x8*)(qp + g * 8);
    f16x8 q1v = *(const f16x8*)(qp + 32 + g * 8);
    const float2* csp = cs + (q0 + w * 16 + c) * 32 + g * 8;
    f16x8 qa, qb_;
#pragma unroll
    for (int e = 0; e < 8; e++) {
        float2 cv = csp[e];
        float x1 = (float)q0v[e], x2 = (float)q1v[e];
        qa[e]  = (_Float16)(x1 * cv.x - x2 * cv.y);
        qb_[e] = (_Float16)(x2 * cv.x + x1 * cv.y);
    }

    const _Float16* Kg = Kh + kvh * 64;
    const int krl = lane >> 3, kcb = (lane & 7) * 16;

#pragma unroll
    for (int q = 0; q < 2; q++) {
        int r = w * 16 + q * 8 + krl;
        gload16(Kg + (long long)r * 512 + ((kcb ^ ((r & 7) << 4)) >> 1),
                LB + (w * 16 + q * 8) * 128);
    }
    __syncthreads();

    float l = 0.f;
    for (int i = 0; i < 16; i++) {
        const char* kbuf = LB + (i & 1) * 16384;
        char* kstage = LB + ((i & 1) ^ 1) * 16384;
        const int nkc = ((i + 1) & 15) * 128;
#pragma unroll
        for (int q = 0; q < 2; q++) {
            int r = w * 16 + q * 8 + krl;
            gload16(Kg + (long long)(nkc + r) * 512 + ((kcb ^ ((r & 7) << 4)) >> 1),
                    kstage + (w * 16 + q * 8) * 128);
        }
#pragma unroll
        for (int t = 0; t < 8; t++) {
            const char* kb = kbuf + (t * 16 + c) * 128;
            f16x8 kb0 = *(const f16x8*)(kb + ((g * 16) ^ swz));
            f16x8 kb1 = *(const f16x8*)(kb + ((64 + g * 16) ^ swz));
            f32x4 acc = {0.f, 0.f, 0.f, 0.f};
            acc = MFMA16(kb0, qa, acc);
            acc = MFMA16(kb1, qb_, acc);
            l += __expf(fminf(acc[0] * 0.125f, 11.f)) + __expf(fminf(acc[1] * 0.125f, 11.f)) +
                 __expf(fminf(acc[2] * 0.125f, 11.f)) + __expf(fminf(acc[3] * 0.125f, 11.f));
        }
        __syncthreads();
    }
    l += __shfl_xor(l, 16, 64);
    l += __shfl_xor(l, 32, 64);
    if (lane < 16)
        Sinv[(long long)h * NSEQ + q0 + w * 16 + c] = 1.0f / l;
}

// ---------------- fused attention v9: single pass, precomputed Sinv (unchanged) -------------
__global__ __launch_bounds__(512) void fused_attn(
    const _Float16* __restrict__ QKV,  // [2048][3072], Q = cols 0..2047 (pre-rope)
    const float2*  __restrict__ cs,    // [2048][32]
    const _Float16* __restrict__ Kh,   // [2048][512] roped
    const _Float16* __restrict__ Vt,   // [512][2048]
    const float* __restrict__ Sinv,    // [32][2048]
    float* __restrict__ attn,          // [32][2048][2048]
    _Float16* __restrict__ AVh)        // [2048][2048]
{
    __shared__ __align__(16) char LB[81920];

    const int h = blockIdx.y, q0 = blockIdx.x * 128;
    const int kvh = h >> 2;
    const int tid = threadIdx.x, lane = tid & 63, w = tid >> 6;
    const int g = lane >> 4, c = lane & 15;
    const int swz = (c & 7) << 4;

    // ---- Q fragment + in-register RoPE ----
    const _Float16* qp = QKV + (long long)(q0 + w * 16 + c) * 3072 + h * 64;
    f16x8 q0v = *(const f16x8*)(qp + g * 8);
    f16x8 q1v = *(const f16x8*)(qp + 32 + g * 8);
    const float2* csp = cs + (q0 + w * 16 + c) * 32 + g * 8;
    f16x8 qa, qb_;
#pragma unroll
    for (int e = 0; e < 8; e++) {
        float2 cv = csp[e];
        float x1 = (float)q0v[e], x2 = (float)q1v[e];
        qa[e]  = (_Float16)(x1 * cv.x - x2 * cv.y);
        qb_[e] = (_Float16)(x2 * cv.x + x1 * cv.y);
    }

    const float inv = Sinv[(long long)h * NSEQ + q0 + w * 16 + c];

    const _Float16* Kg = Kh + kvh * 64;
    const _Float16* Vg = Vt + (long long)(kvh * 64) * NSEQ;
    char* ES = LB + 49152 + w * 4096;  // 16 rows x 256B, wave-private
    float* arow0 = attn + ((long long)h * NSEQ + q0 + w * 16) * NSEQ;

    const int krl = lane >> 3, kcb = (lane & 7) * 16;
    const int vrl = lane >> 4, vcb = (lane & 15) * 16;

    // ---- prologue: stage K chunk 0 into buf 0 ----
#pragma unroll
    for (int q = 0; q < 2; q++) {
        int r = w * 16 + q * 8 + krl;
        gload16(Kg + (long long)r * 512 + ((kcb ^ ((r & 7) << 4)) >> 1),
                LB + (w * 16 + q * 8) * 128);
    }
    __syncthreads();

    f32x4 opv[4] = {};

    for (int i = 0; i < 16; i++) {
        const int kc = i * 128;
        const char* kbuf = LB + (i & 1) * 16384;
        char* kstage = LB + ((i & 1) ^ 1) * 16384;
        const int nkc = ((i + 1) & 15) * 128;
        // stage K(i+1) and V(i)
#pragma unroll
        for (int q = 0; q < 2; q++) {
            int r = w * 16 + q * 8 + krl;
            gload16(Kg + (long long)(nkc + r) * 512 + ((kcb ^ ((r & 7) << 4)) >> 1),
                    kstage + (w * 16 + q * 8) * 128);
        }
#pragma unroll
        for (int q = 0; q < 2; q++) {
            int j = w + q * 8;
            int d = j * 4 + vrl;
            gload16(Vg + (long long)d * NSEQ + kc + ((vcb ^ ((d & 7) << 4)) >> 1),
                    LB + 32768 + j * 1024);
        }
        // ---- hh=0: QK tiles 0-3 -> p -> ES bytes [0,128) ----
#pragma unroll
        for (int t = 0; t < 4; t++) {
            const char* kb = kbuf + (t * 16 + c) * 128;
            f16x8 kb0 = *(const f16x8*)(kb + ((g * 16) ^ swz));
            f16x8 kb1 = *(const f16x8*)(kb + ((64 + g * 16) ^ swz));
            f32x4 acc = {0.f, 0.f, 0.f, 0.f};
            acc = MFMA16(kb0, qa, acc);
            acc = MFMA16(kb1, qb_, acc);
            float p0 = __expf(fminf(acc[0] * 0.125f, 11.f)) * inv;
            float p1 = __expf(fminf(acc[1] * 0.125f, 11.f)) * inv;
            float p2 = __expf(fminf(acc[2] * 0.125f, 11.f)) * inv;
            float p3 = __expf(fminf(acc[3] * 0.125f, 11.f)) * inv;
            f16x2 a01; a01[0] = (_Float16)p0; a01[1] = (_Float16)p1;
            f16x2 a23; a23[0] = (_Float16)p2; a23[1] = (_Float16)p3;
            int b0 = c * 256 + ((t * 32 + g * 8) ^ swz);
            *(f16x2*)(ES + b0) = a01;
            *(f16x2*)(ES + b0 + 4) = a23;
        }
        __asm__ volatile("s_waitcnt lgkmcnt(0)" ::: "memory");
        f16x8 pa0 = *(const f16x8*)(ES + c * 256 + ((g * 16) ^ swz));
        f16x8 pa1 = *(const f16x8*)(ES + c * 256 + ((64 + g * 16) ^ swz));
        __syncthreads();  // V(i) + K(i+1) landed
        // PV cols 0-63
#pragma unroll
        for (int dt = 0; dt < 4; dt++) {
            const char* vrow = LB + 32768 + (dt * 16 + c) * 256;
            f16x8 vb0 = *(const f16x8*)(vrow + ((g * 16) ^ swz));
            f16x8 vb1 = *(const f16x8*)(vrow + ((64 + g * 16) ^ swz));
            opv[dt] = MFMA16(pa0, vb0, opv[dt]);
            opv[dt] = MFMA16(pa1, vb1, opv[dt]);
        }
        // ---- hh=1: QK tiles 4-7 -> ES bytes [128,256) ----
#pragma unroll
        for (int t = 4; t < 8; t++) {
            const char* kb = kbuf + (t * 16 + c) * 128;
            f16x8 kb0 = *(const f16x8*)(kb + ((g * 16) ^ swz));
            f16x8 kb1 = *(const f16x8*)(kb + ((64 + g * 16) ^ swz));
            f32x4 acc = {0.f, 0.f, 0.f, 0.f};
            acc = MFMA16(kb0, qa, acc);
            acc = MFMA16(kb1, qb_, acc);
            float p0 = __expf(fminf(acc[0] * 0.125f, 11.f)) * inv;
            float p1 = __expf(fminf(acc[1] * 0.125f, 11.f)) * inv;
            float p2 = __expf(fminf(acc[2] * 0.125f, 11.f)) * inv;
            float p3 = __expf(fminf(acc[3] * 0.125f, 11.f)) * inv;
            f16x2 a01; a01[0] = (_Float16)p0; a01[1] = (_Float16)p1;
            f16x2 a23; a23[0] = (_Float16)p2; a23[1] = (_Float16)p3;
            int b0 = c * 256 + ((t * 32 + g * 8) ^ swz);
            *(f16x2*)(ES + b0) = a01;
            *(f16x2*)(ES + b0 + 4) = a23;
        }
        __asm__ volatile("s_waitcnt lgkmcnt(0)" ::: "memory");
        f16x8 pa2 = *(const f16x8*)(ES + c * 256 + ((128 + g * 16) ^ swz));
        f16x8 pa3 = *(const f16x8*)(ES + c * 256 + ((192 + g * 16) ^ swz));
        // ---- attn stores: 8 instrs, each 2 rows x 512B contiguous ----
#pragma unroll
        for (int rr = 0; rr < 8; rr++) {
            const int r = 2 * rr + (lane >> 5);
            f16x4 ev = *(const f16x4*)(ES + r * 256 + (((lane & 31) * 8) ^ ((r & 7) << 4)));
            f32x4 o;
            o[0] = (float)ev[0]; o[1] = (float)ev[1];
            o[2] = (float)ev[2]; o[3] = (float)ev[3];
            *(f32x4*)(arow0 + (long long)r * NSEQ + kc + (lane & 31) * 4) = o;
        }
        // PV cols 64-127
#pragma unroll
        for (int dt = 0; dt < 4; dt++) {
            const char* vrow = LB + 32768 + (dt * 16 + c) * 256;
            f16x8 vb2 = *(const f16x8*)(vrow + ((128 + g * 16) ^ swz));
            f16x8 vb3 = *(const f16x8*)(vrow + ((192 + g * 16) ^ swz));
            opv[dt] = MFMA16(pa2, vb2, opv[dt]);
            opv[dt] = MFMA16(pa3, vb3, opv[dt]);
        }
        __syncthreads();  // ES/Vbuf/Kbuf reads done; stages drained
    }

    // ---- AV epilogue (p already normalized) ----
#pragma unroll
    for (int dt = 0; dt < 4; dt++)
#pragma unroll
        for (int j = 0; j < 4; j++)
            AVh[(long long)(q0 + w * 16 + 4 * g + j) * DMODEL + h * 64 + dt * 16 + c] =
                (_Float16)opv[dt][j];
}

extern "C" void kernel_launch(void* const* d_in, const int* in_sizes, int n_in,
                              void* d_out, int out_size, void* d_ws, size_t ws_size,
                              hipStream_t stream) {
    const float* x  = (const float*)d_in[0];
    const float* Wq = (const float*)d_in[1];
    const float* Wk = (const float*)d_in[2];
    const float* Wv = (const float*)d_in[3];
    const float* Wo = (const float*)d_in[4];
    float* out = (float*)d_out;
    float* attn = out + (size_t)NSEQ * DMODEL;

    char* w = (char*)d_ws;
    auto alloc = [&](size_t bytes) { char* p = w; w += (bytes + 255) & ~(size_t)255; return p; };
    const size_t MD = (size_t)NSEQ * DMODEL;        // 4M elems
    const size_t MKV = (size_t)NSEQ * NKV * DK;     // 1M elems
    _Float16* xh    = (_Float16*)alloc(MD * 2);
    _Float16* WqkvT = (_Float16*)alloc((size_t)3072 * 2048 * 2);
    _Float16* WoT   = (_Float16*)alloc(MD * 2);
    float2*   cs    = (float2*)alloc((size_t)NSEQ * 32 * sizeof(float2));
    _Float16* QKV   = (_Float16*)alloc((size_t)2048 * 3072 * 2);
    _Float16* Kh    = (_Float16*)alloc(MKV * 2);
    _Float16* Vt    = (_Float16*)alloc(MKV * 2);
    float*    Sinv  = (float*)alloc((size_t)NHEADS * NSEQ * 4);
    _Float16* AVh   = xh;   // reuse (xh dead after QKV projection)

    prep_weights<<<dim3(64, 64, 5), dim3(32, 8), 0, stream>>>(
        x, Wq, Wk, Wv, Wo, xh, WqkvT, WoT);
    rope_table<<<256, 256, 0, stream>>>(cs);

    // fused QKV projection: [2048][2048] @ [3072][2048]^T -> [2048][3072]
    gemm_lds2<128, 64, 4, 2, _Float16><<<dim3(48, 16), 256, 0, stream>>>(
        xh, WqkvT, QKV, DMODEL, DMODEL, DMODEL, 3072);

    rope_apply16<<<2048, 256, 0, stream>>>(QKV, cs, Kh);
    transpose16p<<<dim3(16, 64), dim3(32, 8), 0, stream>>>(QKV + 2560, Vt, NSEQ, 512, 3072);

    attn_sums<<<dim3(NSEQ / 128, NHEADS), 512, 0, stream>>>(QKV, cs, Kh, Sinv);

    fused_attn<<<dim3(NSEQ / 128, NHEADS), 512, 0, stream>>>(QKV, cs, Kh, Vt, Sinv, attn, AVh);

    gemm_lds2<128, 64, 4, 2, float><<<dim3(32, 16), 256, 0, stream>>>(
        AVh, WoT, out, DMODEL, DMODEL, DMODEL, DMODEL);
}

// Round 15
// 261.703 us; speedup vs baseline: 2.0583x; 1.0088x over previous
//
#include <hip/hip_runtime.h>

typedef _Float16 f16x8 __attribute__((ext_vector_type(8)));
typedef _Float16 f16x4 __attribute__((ext_vector_type(4)));
typedef _Float16 f16x2 __attribute__((ext_vector_type(2)));
typedef float f32x4 __attribute__((ext_vector_type(4)));

#define NSEQ 2048
#define DMODEL 2048
#define NHEADS 32
#define NKV 8
#define DK 64
#define MFMA16(a, b, c) __builtin_amdgcn_mfma_f32_16x16x32_f16(a, b, c, 0, 0, 0)

// async global->LDS, 16B per lane; LDS dest is wave-uniform base + lane*16
__device__ __forceinline__ void gload16(const void* g, void* l) {
    __builtin_amdgcn_global_load_lds(
        (const __attribute__((address_space(1))) void*)g,
        (__attribute__((address_space(3))) void*)l, 16, 0, 0);
}

// ---------------- fused prep: x f32->f16 copy + 4 weight transposes ----------------
__global__ __launch_bounds__(256) void prep_weights(
    const float* __restrict__ x,  const float* __restrict__ Wq,
    const float* __restrict__ Wk, const float* __restrict__ Wv,
    const float* __restrict__ Wo, _Float16* __restrict__ xh,
    _Float16* __restrict__ WqkvT, _Float16* __restrict__ WoT) {
    const int z = blockIdx.z;
    const int tx = threadIdx.x, ty = threadIdx.y; // (32,8)
    if (z == 0) {
        int c0 = blockIdx.x * 32, r0 = blockIdx.y * 32;
#pragma unroll
        for (int i = 0; i < 4; i++) {
            int r = r0 + ty + i * 8;
            xh[(long long)r * DMODEL + c0 + tx] = (_Float16)x[(long long)r * DMODEL + c0 + tx];
        }
        return;
    }
    const float* in; _Float16* out; int C;
    if (z == 1)      { in = Wq; out = WqkvT;                        C = 2048; }
    else if (z == 2) { in = Wk; out = WqkvT + (size_t)2048 * 2048;  C = 512;  }
    else if (z == 3) { in = Wv; out = WqkvT + (size_t)2560 * 2048;  C = 512;  }
    else             { in = Wo; out = WoT;                          C = 2048; }
    int c0 = blockIdx.x * 32, r0 = blockIdx.y * 32;
    if (c0 >= C) return;
    __shared__ float tile[32][33];
#pragma unroll
    for (int i = 0; i < 4; i++) {
        int r = r0 + ty + i * 8;
        tile[ty + i * 8][tx] = in[(long long)r * C + c0 + tx];
    }
    __syncthreads();
#pragma unroll
    for (int i = 0; i < 4; i++) {
        int c = c0 + ty + i * 8;
        out[(long long)c * 2048 + r0 + tx] = (_Float16)tile[tx][ty + i * 8];
    }
}

// ---------------- transpose f16 [R][C] (row pitch) -> f16 [C][R] ----------------
__global__ __launch_bounds__(256) void transpose16p(const _Float16* __restrict__ in,
                                                    _Float16* __restrict__ out,
                                                    int R, int C, int pitch) {
    __shared__ _Float16 tile[32][34];
    int c0 = blockIdx.x * 32, r0 = blockIdx.y * 32;
    int tx = threadIdx.x, ty = threadIdx.y; // (32,8)
#pragma unroll
    for (int i = 0; i < 4; i++) {
        int r = r0 + ty + i * 8;
        tile[ty + i * 8][tx] = in[(long long)r * pitch + c0 + tx];
    }
    __syncthreads();
#pragma unroll
    for (int i = 0; i < 4; i++) {
        int c = c0 + ty + i * 8;
        out[(long long)c * R + r0 + tx] = tile[tx][ty + i * 8];
    }
}

// ---------------- RoPE cos/sin table ----------------
__global__ void rope_table(float2* __restrict__ cs) {
    int idx = blockIdx.x * blockDim.x + threadIdx.x; // 65536 total
    int n = idx >> 5, j = idx & 31;
    float e = (2.0f * j) / 64.0f;
    float invf = 1.0f / powf(10000.0f, e);
    float ang = (float)n * invf;
    float2 v; v.x = cosf(ang); v.y = sinf(ang);
    cs[idx] = v;
}

// ---------------- RoPE apply for K: reads K cols of QKV [2048][3072], writes Kh [2048][512] --
__global__ void rope_apply16(const _Float16* __restrict__ QKV, const float2* __restrict__ cs,
                             _Float16* __restrict__ out) {
    int idx = blockIdx.x * blockDim.x + threadIdx.x; // 2048*256
    int n = idx >> 8, rem = idx & 255;
    int hk = rem >> 5, j = rem & 31;
    float2 c = cs[n * 32 + j];
    const _Float16* in = QKV + (long long)n * 3072 + 2048 + hk * 64;
    float x1 = (float)in[j], x2 = (float)in[j + 32];
    long long ob = (long long)n * 512 + hk * 64;
    out[ob + j]      = (_Float16)(x1 * c.x - x2 * c.y);
    out[ob + j + 32] = (_Float16)(x2 * c.x + x1 * c.y);
}

// ---------------- GEMM v2: BK=64, XOR-swizzled LDS rows, C[M,N] = A @ Bt^T ----------------
template <int BM, int BN, int MF, int NF, typename OutT>
__global__ __launch_bounds__(256) void gemm_lds2(const _Float16* __restrict__ Ap,
                                                 const _Float16* __restrict__ Bt,
                                                 OutT* __restrict__ C,
                                                 int K, int lda, int ldb, int ldc) {
    __shared__ __align__(16) _Float16 As[BM * 64];
    __shared__ __align__(16) _Float16 Bs[BN * 64];

    const int tid = threadIdx.x;
    const int lane = tid & 63, w = tid >> 6;
    constexpr int WC = BN / (NF * 16);
    const int wr = w / WC, wc = w % WC;
    const int wm = wr * MF * 16, wn = wc * NF * 16;
    const int am = lane & 15;
    const int g = lane >> 4;
    const int aswz = (am & 7) << 4;

    f32x4 acc[MF][NF] = {};

    const long long a_row0 = (long long)blockIdx.y * BM * lda;
    const long long b_row0 = (long long)blockIdx.x * BN * ldb;

    const int srow = lane >> 3;        // staging: row within 8-row group
    const int scolb = (lane & 7) * 16; // staging: byte col within 128B row

    for (int kt = 0; kt < K; kt += 64) {
#pragma unroll
        for (int q = 0; q < BM / 32; q++) {
            const int rA = w * (BM / 4) + q * 8;
            const int r = rA + srow;
            gload16(Ap + a_row0 + (long long)r * lda + kt + ((scolb ^ ((r & 7) << 4)) >> 1),
                    &As[rA * 64]);
        }
#pragma unroll
        for (int q = 0; q < BN / 32; q++) {
            const int rB = w * (BN / 4) + q * 8;
            const int r = rB + srow;
            gload16(Bt + b_row0 + (long long)r * ldb + kt + ((scolb ^ ((r & 7) << 4)) >> 1),
                    &Bs[rB * 64]);
        }
        __syncthreads();

#pragma unroll
        for (int ks = 0; ks < 2; ks++) {
            const int koff = ((ks * 64 + g * 16) ^ aswz) >> 1; // byte->half
            f16x8 af[MF], bf[NF];
#pragma unroll
            for (int m = 0; m < MF; m++)
                af[m] = *(const f16x8*)&As[(wm + m * 16 + am) * 64 + koff];
#pragma unroll
            for (int n = 0; n < NF; n++)
                bf[n] = *(const f16x8*)&Bs[(wn + n * 16 + am) * 64 + koff];
#pragma unroll
            for (int m = 0; m < MF; m++)
#pragma unroll
                for (int n = 0; n < NF; n++)
                    acc[m][n] = MFMA16(af[m], bf[n], acc[m][n]);
        }
        __syncthreads();
    }

    const int rb = blockIdx.y * BM + wm + (lane >> 4) * 4;
    const int cb = blockIdx.x * BN + wn + am;
#pragma unroll
    for (int m = 0; m < MF; m++)
#pragma unroll
        for (int n = 0; n < NF; n++)
#pragma unroll
            for (int j = 0; j < 4; j++)
                C[(long long)(rb + m * 16 + j) * ldc + cb + n * 16] = (OutT)acc[m][n][j];
}

// ---------------- kernel A: row sums -> Sinv[32][2048] (unchanged) ----------------
__global__ __launch_bounds__(512) void attn_sums(
    const _Float16* __restrict__ QKV,  // [2048][3072] (Q cols 0..2047, pre-rope)
    const float2*  __restrict__ cs,    // [2048][32]
    const _Float16* __restrict__ Kh,   // [2048][512] roped
    float* __restrict__ Sinv)          // [32][2048]
{
    __shared__ __align__(16) char LB[32768]; // Kbuf[2] 2x16KB

    const int h = blockIdx.y, q0 = blockIdx.x * 128;
    const int kvh = h >> 2;
    const int tid = threadIdx.x, lane = tid & 63, w = tid >> 6;
    const int g = lane >> 4, c = lane & 15;
    const int swz = (c & 7) << 4;

    const _Float16* qp = QKV + (long long)(q0 + w * 16 + c) * 3072 + h * 64;
    f16x8 q0v = *(const f16x8*)(qp + g * 8);
    f16x8 q1v = *(const f16x8*)(qp + 32 + g * 8);
    const float2* csp = cs + (q0 + w * 16 + c) * 32 + g * 8;
    f16x8 qa, qb_;
#pragma unroll
    for (int e = 0; e < 8; e++) {
        float2 cv = csp[e];
        float x1 = (float)q0v[e], x2 = (float)q1v[e];
        qa[e]  = (_Float16)(x1 * cv.x - x2 * cv.y);
        qb_[e] = (_Float16)(x2 * cv.x + x1 * cv.y);
    }

    const _Float16* Kg = Kh + kvh * 64;
    const int krl = lane >> 3, kcb = (lane & 7) * 16;

#pragma unroll
    for (int q = 0; q < 2; q++) {
        int r = w * 16 + q * 8 + krl;
        gload16(Kg + (long long)r * 512 + ((kcb ^ ((r & 7) << 4)) >> 1),
                LB + (w * 16 + q * 8) * 128);
    }
    __syncthreads();

    float l = 0.f;
    for (int i = 0; i < 16; i++) {
        const char* kbuf = LB + (i & 1) * 16384;
        char* kstage = LB + ((i & 1) ^ 1) * 16384;
        const int nkc = ((i + 1) & 15) * 128;
#pragma unroll
        for (int q = 0; q < 2; q++) {
            int r = w * 16 + q * 8 + krl;
            gload16(Kg + (long long)(nkc + r) * 512 + ((kcb ^ ((r & 7) << 4)) >> 1),
                    kstage + (w * 16 + q * 8) * 128);
        }
#pragma unroll
        for (int t = 0; t < 8; t++) {
            const char* kb = kbuf + (t * 16 + c) * 128;
            f16x8 kb0 = *(const f16x8*)(kb + ((g * 16) ^ swz));
            f16x8 kb1 = *(const f16x8*)(kb + ((64 + g * 16) ^ swz));
            f32x4 acc = {0.f, 0.f, 0.f, 0.f};
            acc = MFMA16(kb0, qa, acc);
            acc = MFMA16(kb1, qb_, acc);
            l += __expf(fminf(acc[0] * 0.125f, 11.f)) + __expf(fminf(acc[1] * 0.125f, 11.f)) +
                 __expf(fminf(acc[2] * 0.125f, 11.f)) + __expf(fminf(acc[3] * 0.125f, 11.f));
        }
        __syncthreads();
    }
    l += __shfl_xor(l, 16, 64);
    l += __shfl_xor(l, 32, 64);
    if (lane < 16)
        Sinv[(long long)h * NSEQ + q0 + w * 16 + c] = 1.0f / l;
}

// ---------------- fused attention v10: stores issued right after the full barrier ----------
// Per chunk: __syncthreads (drains K(i)/V(i) gloads; old stores had a FULL chunk to drain)
//  -> stores p(i-1) from ES (fire-and-forget, max drain window)
//  -> stage K(i+1) -> QK(i)->ES -> PV(i) (all 128 cols)
//  -> lgkm-only raw barrier (no vmcnt: protects only LDS reads) -> stage V(i+1).
// Store drain now overlaps compute: T -> max(compute, HBM-write) instead of sum.
// LDS: Kbuf[2] 32K @0, Vbuf 16K @32768, ES 32K @49152 = 80KB -> 2 blocks/CU.
__global__ __launch_bounds__(512) void fused_attn(
    const _Float16* __restrict__ QKV,  // [2048][3072], Q = cols 0..2047 (pre-rope)
    const float2*  __restrict__ cs,    // [2048][32]
    const _Float16* __restrict__ Kh,   // [2048][512] roped
    const _Float16* __restrict__ Vt,   // [512][2048]
    const float* __restrict__ Sinv,    // [32][2048]
    float* __restrict__ attn,          // [32][2048][2048]
    _Float16* __restrict__ AVh)        // [2048][2048]
{
    __shared__ __align__(16) char LB[81920];

    const int h = blockIdx.y, q0 = blockIdx.x * 128;
    const int kvh = h >> 2;
    const int tid = threadIdx.x, lane = tid & 63, w = tid >> 6;
    const int g = lane >> 4, c = lane & 15;
    const int swz = (c & 7) << 4;

    // ---- Q fragment + in-register RoPE ----
    const _Float16* qp = QKV + (long long)(q0 + w * 16 + c) * 3072 + h * 64;
    f16x8 q0v = *(const f16x8*)(qp + g * 8);
    f16x8 q1v = *(const f16x8*)(qp + 32 + g * 8);
    const float2* csp = cs + (q0 + w * 16 + c) * 32 + g * 8;
    f16x8 qa, qb_;
#pragma unroll
    for (int e = 0; e < 8; e++) {
        float2 cv = csp[e];
        float x1 = (float)q0v[e], x2 = (float)q1v[e];
        qa[e]  = (_Float16)(x1 * cv.x - x2 * cv.y);
        qb_[e] = (_Float16)(x2 * cv.x + x1 * cv.y);
    }

    const float inv = Sinv[(long long)h * NSEQ + q0 + w * 16 + c];

    const _Float16* Kg = Kh + kvh * 64;
    const _Float16* Vg = Vt + (long long)(kvh * 64) * NSEQ;
    char* ES = LB + 49152 + w * 4096;  // 16 rows x 256B, wave-private
    float* arow0 = attn + ((long long)h * NSEQ + q0 + w * 16) * NSEQ;

    const int krl = lane >> 3, kcb = (lane & 7) * 16;
    const int vrl = lane >> 4, vcb = (lane & 15) * 16;

    // ---- prologue: stage K(0) -> Kbuf[0], V(0) -> Vbuf ----
#pragma unroll
    for (int q = 0; q < 2; q++) {
        int r = w * 16 + q * 8 + krl;
        gload16(Kg + (long long)r * 512 + ((kcb ^ ((r & 7) << 4)) >> 1),
                LB + (w * 16 + q * 8) * 128);
    }
#pragma unroll
    for (int q = 0; q < 2; q++) {
        int j = w + q * 8;
        int d = j * 4 + vrl;
        gload16(Vg + (long long)d * NSEQ + ((vcb ^ ((d & 7) << 4)) >> 1),
                LB + 32768 + j * 1024);
    }

    f32x4 opv[4] = {};

    for (int i = 0; i < 16; i++) {
        const int kc = i * 128;
        const char* kbuf = LB + (i & 1) * 16384;
        char* kstage = LB + ((i & 1) ^ 1) * 16384;
        const int nkc = ((i + 1) & 15) * 128;

        __syncthreads();  // FULL: K(i)/V(i) gloads landed; old stores long since drained

        // ---- stores of p(i-1): issued immediately after the vmcnt barrier ----
        if (i > 0) {
            const int pkc = kc - 128;
#pragma unroll
            for (int rr = 0; rr < 8; rr++) {
                const int r = 2 * rr + (lane >> 5);
                f16x4 ev = *(const f16x4*)(ES + r * 256 + (((lane & 31) * 8) ^ ((r & 7) << 4)));
                f32x4 o;
                o[0] = (float)ev[0]; o[1] = (float)ev[1];
                o[2] = (float)ev[2]; o[3] = (float)ev[3];
                *(f32x4*)(arow0 + (long long)r * NSEQ + pkc + (lane & 31) * 4) = o;
            }
            __asm__ volatile("s_waitcnt lgkmcnt(0)" ::: "memory"); // ES reads done before overwrite
            __builtin_amdgcn_sched_barrier(0);
        }

        // ---- stage K(i+1) -> kstage ----
#pragma unroll
        for (int q = 0; q < 2; q++) {
            int r = w * 16 + q * 8 + krl;
            gload16(Kg + (long long)(nkc + r) * 512 + ((kcb ^ ((r & 7) << 4)) >> 1),
                    kstage + (w * 16 + q * 8) * 128);
        }

        // ---- QK chunk i -> p -> ES ----
#pragma unroll
        for (int t = 0; t < 8; t++) {
            const char* kb = kbuf + (t * 16 + c) * 128;
            f16x8 kb0 = *(const f16x8*)(kb + ((g * 16) ^ swz));
            f16x8 kb1 = *(const f16x8*)(kb + ((64 + g * 16) ^ swz));
            f32x4 acc = {0.f, 0.f, 0.f, 0.f};
            acc = MFMA16(kb0, qa, acc);
            acc = MFMA16(kb1, qb_, acc);
            float p0 = __expf(fminf(acc[0] * 0.125f, 11.f)) * inv;
            float p1 = __expf(fminf(acc[1] * 0.125f, 11.f)) * inv;
            float p2 = __expf(fminf(acc[2] * 0.125f, 11.f)) * inv;
            float p3 = __expf(fminf(acc[3] * 0.125f, 11.f)) * inv;
            f16x2 a01; a01[0] = (_Float16)p0; a01[1] = (_Float16)p1;
            f16x2 a23; a23[0] = (_Float16)p2; a23[1] = (_Float16)p3;
            int b0 = c * 256 + ((t * 32 + g * 8) ^ swz);
            *(f16x2*)(ES + b0) = a01;
            *(f16x2*)(ES + b0 + 4) = a23;
        }
        __asm__ volatile("s_waitcnt lgkmcnt(0)" ::: "memory");
        f16x8 pa0 = *(const f16x8*)(ES + c * 256 + ((g * 16) ^ swz));
        f16x8 pa1 = *(const f16x8*)(ES + c * 256 + ((64 + g * 16) ^ swz));
        f16x8 pa2 = *(const f16x8*)(ES + c * 256 + ((128 + g * 16) ^ swz));
        f16x8 pa3 = *(const f16x8*)(ES + c * 256 + ((192 + g * 16) ^ swz));

        // ---- PV all 128 cols (V(i) from Vbuf) ----
#pragma unroll
        for (int dt = 0; dt < 4; dt++) {
            const char* vrow = LB + 32768 + (dt * 16 + c) * 256;
            f16x8 vb0 = *(const f16x8*)(vrow + ((g * 16) ^ swz));
            f16x8 vb1 = *(const f16x8*)(vrow + ((64 + g * 16) ^ swz));
            f16x8 vb2 = *(const f16x8*)(vrow + ((128 + g * 16) ^ swz));
            f16x8 vb3 = *(const f16x8*)(vrow + ((192 + g * 16) ^ swz));
            opv[dt] = MFMA16(pa0, vb0, opv[dt]);
            opv[dt] = MFMA16(pa1, vb1, opv[dt]);
            opv[dt] = MFMA16(pa2, vb2, opv[dt]);
            opv[dt] = MFMA16(pa3, vb3, opv[dt]);
        }

        // ---- lgkm-only barrier: all waves done reading Kbuf[cur]/Vbuf (no vmcnt drain) ----
        __asm__ volatile("s_waitcnt lgkmcnt(0)" ::: "memory");
        __builtin_amdgcn_s_barrier();

        // ---- stage V(i+1) -> Vbuf ----
#pragma unroll
        for (int q = 0; q < 2; q++) {
            int j = w + q * 8;
            int d = j * 4 + vrl;
            gload16(Vg + (long long)d * NSEQ + nkc + ((vcb ^ ((d & 7) << 4)) >> 1),
                    LB + 32768 + j * 1024);
        }
    }

    // ---- epilogue: stores of p(15) ----
    {
        const int pkc = 15 * 128;
#pragma unroll
        for (int rr = 0; rr < 8; rr++) {
            const int r = 2 * rr + (lane >> 5);
            f16x4 ev = *(const f16x4*)(ES + r * 256 + (((lane & 31) * 8) ^ ((r & 7) << 4)));
            f32x4 o;
            o[0] = (float)ev[0]; o[1] = (float)ev[1];
            o[2] = (float)ev[2]; o[3] = (float)ev[3];
            *(f32x4*)(arow0 + (long long)r * NSEQ + pkc + (lane & 31) * 4) = o;
        }
    }

    // ---- AV epilogue (p already normalized) ----
#pragma unroll
    for (int dt = 0; dt < 4; dt++)
#pragma unroll
        for (int j = 0; j < 4; j++)
            AVh[(long long)(q0 + w * 16 + 4 * g + j) * DMODEL + h * 64 + dt * 16 + c] =
                (_Float16)opv[dt][j];
}

extern "C" void kernel_launch(void* const* d_in, const int* in_sizes, int n_in,
                              void* d_out, int out_size, void* d_ws, size_t ws_size,
                              hipStream_t stream) {
    const float* x  = (const float*)d_in[0];
    const float* Wq = (const float*)d_in[1];
    const float* Wk = (const float*)d_in[2];
    const float* Wv = (const float*)d_in[3];
    const float* Wo = (const float*)d_in[4];
    float* out = (float*)d_out;
    float* attn = out + (size_t)NSEQ * DMODEL;

    char* w = (char*)d_ws;
    auto alloc = [&](size_t bytes) { char* p = w; w += (bytes + 255) & ~(size_t)255; return p; };
    const size_t MD = (size_t)NSEQ * DMODEL;        // 4M elems
    const size_t MKV = (size_t)NSEQ * NKV * DK;     // 1M elems
    _Float16* xh    = (_Float16*)alloc(MD * 2);
    _Float16* WqkvT = (_Float16*)alloc((size_t)3072 * 2048 * 2);
    _Float16* WoT   = (_Float16*)alloc(MD * 2);
    float2*   cs    = (float2*)alloc((size_t)NSEQ * 32 * sizeof(float2));
    _Float16* QKV   = (_Float16*)alloc((size_t)2048 * 3072 * 2);
    _Float16* Kh    = (_Float16*)alloc(MKV * 2);
    _Float16* Vt    = (_Float16*)alloc(MKV * 2);
    float*    Sinv  = (float*)alloc((size_t)NHEADS * NSEQ * 4);
    _Float16* AVh   = xh;   // reuse (xh dead after QKV projection)

    prep_weights<<<dim3(64, 64, 5), dim3(32, 8), 0, stream>>>(
        x, Wq, Wk, Wv, Wo, xh, WqkvT, WoT);
    rope_table<<<256, 256, 0, stream>>>(cs);

    // fused QKV projection: [2048][2048] @ [3072][2048]^T -> [2048][3072]
    gemm_lds2<128, 64, 4, 2, _Float16><<<dim3(48, 16), 256, 0, stream>>>(
        xh, WqkvT, QKV, DMODEL, DMODEL, DMODEL, 3072);

    rope_apply16<<<2048, 256, 0, stream>>>(QKV, cs, Kh);
    transpose16p<<<dim3(16, 64), dim3(32, 8), 0, stream>>>(QKV + 2560, Vt, NSEQ, 512, 3072);

    attn_sums<<<dim3(NSEQ / 128, NHEADS), 512, 0, stream>>>(QKV, cs, Kh, Sinv);

    fused_attn<<<dim3(NSEQ / 128, NHEADS), 512, 0, stream>>>(QKV, cs, Kh, Vt, Sinv, attn, AVh);

    gemm_lds2<128, 64, 4, 2, float><<<dim3(32, 16), 256, 0, stream>>>(
        AVh, WoT, out, DMODEL, DMODEL, DMODEL, DMODEL);
}

// Round 16
// 256.801 us; speedup vs baseline: 2.0976x; 1.0191x over previous
//
#include <hip/hip_runtime.h>

typedef _Float16 f16x8 __attribute__((ext_vector_type(8)));
typedef _Float16 f16x4 __attribute__((ext_vector_type(4)));
typedef _Float16 f16x2 __attribute__((ext_vector_type(2)));
typedef float f32x4 __attribute__((ext_vector_type(4)));

#define NSEQ 2048
#define DMODEL 2048
#define NHEADS 32
#define NKV 8
#define DK 64
#define MFMA16(a, b, c) __builtin_amdgcn_mfma_f32_16x16x32_f16(a, b, c, 0, 0, 0)

// async global->LDS, 16B per lane; LDS dest is wave-uniform base + lane*16
__device__ __forceinline__ void gload16(const void* g, void* l) {
    __builtin_amdgcn_global_load_lds(
        (const __attribute__((address_space(1))) void*)g,
        (__attribute__((address_space(3))) void*)l, 16, 0, 0);
}

// ---------------- fused prep: x f32->f16 copy + 4 weight transposes ----------------
__global__ __launch_bounds__(256) void prep_weights(
    const float* __restrict__ x,  const float* __restrict__ Wq,
    const float* __restrict__ Wk, const float* __restrict__ Wv,
    const float* __restrict__ Wo, _Float16* __restrict__ xh,
    _Float16* __restrict__ WqkvT, _Float16* __restrict__ WoT) {
    const int z = blockIdx.z;
    const int tx = threadIdx.x, ty = threadIdx.y; // (32,8)
    if (z == 0) {
        int c0 = blockIdx.x * 32, r0 = blockIdx.y * 32;
#pragma unroll
        for (int i = 0; i < 4; i++) {
            int r = r0 + ty + i * 8;
            xh[(long long)r * DMODEL + c0 + tx] = (_Float16)x[(long long)r * DMODEL + c0 + tx];
        }
        return;
    }
    const float* in; _Float16* out; int C;
    if (z == 1)      { in = Wq; out = WqkvT;                        C = 2048; }
    else if (z == 2) { in = Wk; out = WqkvT + (size_t)2048 * 2048;  C = 512;  }
    else if (z == 3) { in = Wv; out = WqkvT + (size_t)2560 * 2048;  C = 512;  }
    else             { in = Wo; out = WoT;                          C = 2048; }
    int c0 = blockIdx.x * 32, r0 = blockIdx.y * 32;
    if (c0 >= C) return;
    __shared__ float tile[32][33];
#pragma unroll
    for (int i = 0; i < 4; i++) {
        int r = r0 + ty + i * 8;
        tile[ty + i * 8][tx] = in[(long long)r * C + c0 + tx];
    }
    __syncthreads();
#pragma unroll
    for (int i = 0; i < 4; i++) {
        int c = c0 + ty + i * 8;
        out[(long long)c * 2048 + r0 + tx] = (_Float16)tile[tx][ty + i * 8];
    }
}

// ---------------- transpose f16 [R][C] (row pitch) -> f16 [C][R] ----------------
__global__ __launch_bounds__(256) void transpose16p(const _Float16* __restrict__ in,
                                                    _Float16* __restrict__ out,
                                                    int R, int C, int pitch) {
    __shared__ _Float16 tile[32][34];
    int c0 = blockIdx.x * 32, r0 = blockIdx.y * 32;
    int tx = threadIdx.x, ty = threadIdx.y; // (32,8)
#pragma unroll
    for (int i = 0; i < 4; i++) {
        int r = r0 + ty + i * 8;
        tile[ty + i * 8][tx] = in[(long long)r * pitch + c0 + tx];
    }
    __syncthreads();
#pragma unroll
    for (int i = 0; i < 4; i++) {
        int c = c0 + ty + i * 8;
        out[(long long)c * R + r0 + tx] = tile[tx][ty + i * 8];
    }
}

// ---------------- RoPE cos/sin table ----------------
__global__ void rope_table(float2* __restrict__ cs) {
    int idx = blockIdx.x * blockDim.x + threadIdx.x; // 65536 total
    int n = idx >> 5, j = idx & 31;
    float e = (2.0f * j) / 64.0f;
    float invf = 1.0f / powf(10000.0f, e);
    float ang = (float)n * invf;
    float2 v; v.x = cosf(ang); v.y = sinf(ang);
    cs[idx] = v;
}

// ---------------- RoPE apply for K: reads K cols of QKV [2048][3072], writes Kh [2048][512] --
__global__ void rope_apply16(const _Float16* __restrict__ QKV, const float2* __restrict__ cs,
                             _Float16* __restrict__ out) {
    int idx = blockIdx.x * blockDim.x + threadIdx.x; // 2048*256
    int n = idx >> 8, rem = idx & 255;
    int hk = rem >> 5, j = rem & 31;
    float2 c = cs[n * 32 + j];
    const _Float16* in = QKV + (long long)n * 3072 + 2048 + hk * 64;
    float x1 = (float)in[j], x2 = (float)in[j + 32];
    long long ob = (long long)n * 512 + hk * 64;
    out[ob + j]      = (_Float16)(x1 * c.x - x2 * c.y);
    out[ob + j + 32] = (_Float16)(x2 * c.x + x1 * c.y);
}

// ---------------- GEMM v3: double-buffered LDS, ONE barrier per K-step, XCD swizzle --------
// dbuf + stage-after-barrier: the barrier drains the stage issued one iteration ago (which
// had the whole compute phase in flight) — halves the vmcnt(0) drains of gemm_lds2.
// XCD swizzle (bijective; requires nwg%8==0): consecutive work-ids share the A-panel within
// one XCD's L2. Staging bytes / swizzle / read offsets identical to gemm_lds2.
template <int BM, int BN, int MF, int NF, typename OutT>
__global__ __launch_bounds__(256) void gemm_lds3(const _Float16* __restrict__ Ap,
                                                 const _Float16* __restrict__ Bt,
                                                 OutT* __restrict__ C,
                                                 int K, int lda, int ldb, int ldc) {
    __shared__ __align__(16) _Float16 As[2][BM * 64];
    __shared__ __align__(16) _Float16 Bs[2][BN * 64];

    const int tid = threadIdx.x;
    const int lane = tid & 63, w = tid >> 6;
    constexpr int WC = BN / (NF * 16);
    const int wr = w / WC, wc = w % WC;
    const int wm = wr * MF * 16, wn = wc * NF * 16;
    const int am = lane & 15;
    const int g = lane >> 4;
    const int aswz = (am & 7) << 4;

    // bijective XCD remap of flattened block id (nwg % 8 == 0 for all our grids)
    const int nwg = gridDim.x * gridDim.y;
    int fid = blockIdx.y * gridDim.x + blockIdx.x;
    fid = (fid & 7) * (nwg >> 3) + (fid >> 3);
    const int bx = fid % gridDim.x, by = fid / gridDim.x;

    f32x4 acc[MF][NF] = {};

    const long long a_row0 = (long long)by * BM * lda;
    const long long b_row0 = (long long)bx * BN * ldb;

    const int srow = lane >> 3;        // staging: row within 8-row group
    const int scolb = (lane & 7) * 16; // staging: byte col within 128B row

    auto stage = [&](int kt, int buf) {
#pragma unroll
        for (int q = 0; q < BM / 32; q++) {
            const int rA = w * (BM / 4) + q * 8;
            const int r = rA + srow;
            gload16(Ap + a_row0 + (long long)r * lda + kt + ((scolb ^ ((r & 7) << 4)) >> 1),
                    &As[buf][rA * 64]);
        }
#pragma unroll
        for (int q = 0; q < BN / 32; q++) {
            const int rB = w * (BN / 4) + q * 8;
            const int r = rB + srow;
            gload16(Bt + b_row0 + (long long)r * ldb + kt + ((scolb ^ ((r & 7) << 4)) >> 1),
                    &Bs[buf][rB * 64]);
        }
    };

    stage(0, 0);
    int cur = 0;

    for (int kt = 0; kt < K; kt += 64) {
        __syncthreads();                 // drains stage(kt) — issued one full phase ago
        if (kt + 64 < K) stage(kt + 64, cur ^ 1);

#pragma unroll
        for (int ks = 0; ks < 2; ks++) {
            const int koff = ((ks * 64 + g * 16) ^ aswz) >> 1; // byte->half
            f16x8 af[MF], bf[NF];
#pragma unroll
            for (int m = 0; m < MF; m++)
                af[m] = *(const f16x8*)&As[cur][(wm + m * 16 + am) * 64 + koff];
#pragma unroll
            for (int n = 0; n < NF; n++)
                bf[n] = *(const f16x8*)&Bs[cur][(wn + n * 16 + am) * 64 + koff];
#pragma unroll
            for (int m = 0; m < MF; m++)
#pragma unroll
                for (int n = 0; n < NF; n++)
                    acc[m][n] = MFMA16(af[m], bf[n], acc[m][n]);
        }
        cur ^= 1;
    }

    const int rb = by * BM + wm + (lane >> 4) * 4;
    const int cb = bx * BN + wn + am;
#pragma unroll
    for (int m = 0; m < MF; m++)
#pragma unroll
        for (int n = 0; n < NF; n++)
#pragma unroll
            for (int j = 0; j < 4; j++)
                C[(long long)(rb + m * 16 + j) * ldc + cb + n * 16] = (OutT)acc[m][n][j];
}

// ---------------- kernel A: row sums -> Sinv[32][2048] (unchanged) ----------------
__global__ __launch_bounds__(512) void attn_sums(
    const _Float16* __restrict__ QKV,  // [2048][3072] (Q cols 0..2047, pre-rope)
    const float2*  __restrict__ cs,    // [2048][32]
    const _Float16* __restrict__ Kh,   // [2048][512] roped
    float* __restrict__ Sinv)          // [32][2048]
{
    __shared__ __align__(16) char LB[32768]; // Kbuf[2] 2x16KB

    const int h = blockIdx.y, q0 = blockIdx.x * 128;
    const int kvh = h >> 2;
    const int tid = threadIdx.x, lane = tid & 63, w = tid >> 6;
    const int g = lane >> 4, c = lane & 15;
    const int swz = (c & 7) << 4;

    const _Float16* qp = QKV + (long long)(q0 + w * 16 + c) * 3072 + h * 64;
    f16x8 q0v = *(const f16x8*)(qp + g * 8);
    f16x8 q1v = *(const f16x8*)(qp + 32 + g * 8);
    const float2* csp = cs + (q0 + w * 16 + c) * 32 + g * 8;
    f16x8 qa, qb_;
#pragma unroll
    for (int e = 0; e < 8; e++) {
        float2 cv = csp[e];
        float x1 = (float)q0v[e], x2 = (float)q1v[e];
        qa[e]  = (_Float16)(x1 * cv.x - x2 * cv.y);
        qb_[e] = (_Float16)(x2 * cv.x + x1 * cv.y);
    }

    const _Float16* Kg = Kh + kvh * 64;
    const int krl = lane >> 3, kcb = (lane & 7) * 16;

#pragma unroll
    for (int q = 0; q < 2; q++) {
        int r = w * 16 + q * 8 + krl;
        gload16(Kg + (long long)r * 512 + ((kcb ^ ((r & 7) << 4)) >> 1),
                LB + (w * 16 + q * 8) * 128);
    }
    __syncthreads();

    float l = 0.f;
    for (int i = 0; i < 16; i++) {
        const char* kbuf = LB + (i & 1) * 16384;
        char* kstage = LB + ((i & 1) ^ 1) * 16384;
        const int nkc = ((i + 1) & 15) * 128;
#pragma unroll
        for (int q = 0; q < 2; q++) {
            int r = w * 16 + q * 8 + krl;
            gload16(Kg + (long long)(nkc + r) * 512 + ((kcb ^ ((r & 7) << 4)) >> 1),
                    kstage + (w * 16 + q * 8) * 128);
        }
#pragma unroll
        for (int t = 0; t < 8; t++) {
            const char* kb = kbuf + (t * 16 + c) * 128;
            f16x8 kb0 = *(const f16x8*)(kb + ((g * 16) ^ swz));
            f16x8 kb1 = *(const f16x8*)(kb + ((64 + g * 16) ^ swz));
            f32x4 acc = {0.f, 0.f, 0.f, 0.f};
            acc = MFMA16(kb0, qa, acc);
            acc = MFMA16(kb1, qb_, acc);
            l += __expf(fminf(acc[0] * 0.125f, 11.f)) + __expf(fminf(acc[1] * 0.125f, 11.f)) +
                 __expf(fminf(acc[2] * 0.125f, 11.f)) + __expf(fminf(acc[3] * 0.125f, 11.f));
        }
        __syncthreads();
    }
    l += __shfl_xor(l, 16, 64);
    l += __shfl_xor(l, 32, 64);
    if (lane < 16)
        Sinv[(long long)h * NSEQ + q0 + w * 16 + c] = 1.0f / l;
}

// ---------------- fused attention v10 (unchanged from round 15) ----------------
__global__ __launch_bounds__(512) void fused_attn(
    const _Float16* __restrict__ QKV,  // [2048][3072], Q = cols 0..2047 (pre-rope)
    const float2*  __restrict__ cs,    // [2048][32]
    const _Float16* __restrict__ Kh,   // [2048][512] roped
    const _Float16* __restrict__ Vt,   // [512][2048]
    const float* __restrict__ Sinv,    // [32][2048]
    float* __restrict__ attn,          // [32][2048][2048]
    _Float16* __restrict__ AVh)        // [2048][2048]
{
    __shared__ __align__(16) char LB[81920];

    const int h = blockIdx.y, q0 = blockIdx.x * 128;
    const int kvh = h >> 2;
    const int tid = threadIdx.x, lane = tid & 63, w = tid >> 6;
    const int g = lane >> 4, c = lane & 15;
    const int swz = (c & 7) << 4;

    // ---- Q fragment + in-register RoPE ----
    const _Float16* qp = QKV + (long long)(q0 + w * 16 + c) * 3072 + h * 64;
    f16x8 q0v = *(const f16x8*)(qp + g * 8);
    f16x8 q1v = *(const f16x8*)(qp + 32 + g * 8);
    const float2* csp = cs + (q0 + w * 16 + c) * 32 + g * 8;
    f16x8 qa, qb_;
#pragma unroll
    for (int e = 0; e < 8; e++) {
        float2 cv = csp[e];
        float x1 = (float)q0v[e], x2 = (float)q1v[e];
        qa[e]  = (_Float16)(x1 * cv.x - x2 * cv.y);
        qb_[e] = (_Float16)(x2 * cv.x + x1 * cv.y);
    }

    const float inv = Sinv[(long long)h * NSEQ + q0 + w * 16 + c];

    const _Float16* Kg = Kh + kvh * 64;
    const _Float16* Vg = Vt + (long long)(kvh * 64) * NSEQ;
    char* ES = LB + 49152 + w * 4096;  // 16 rows x 256B, wave-private
    float* arow0 = attn + ((long long)h * NSEQ + q0 + w * 16) * NSEQ;

    const int krl = lane >> 3, kcb = (lane & 7) * 16;
    const int vrl = lane >> 4, vcb = (lane & 15) * 16;

    // ---- prologue: stage K(0) -> Kbuf[0], V(0) -> Vbuf ----
#pragma unroll
    for (int q = 0; q < 2; q++) {
        int r = w * 16 + q * 8 + krl;
        gload16(Kg + (long long)r * 512 + ((kcb ^ ((r & 7) << 4)) >> 1),
                LB + (w * 16 + q * 8) * 128);
    }
#pragma unroll
    for (int q = 0; q < 2; q++) {
        int j = w + q * 8;
        int d = j * 4 + vrl;
        gload16(Vg + (long long)d * NSEQ + ((vcb ^ ((d & 7) << 4)) >> 1),
                LB + 32768 + j * 1024);
    }

    f32x4 opv[4] = {};

    for (int i = 0; i < 16; i++) {
        const int kc = i * 128;
        const char* kbuf = LB + (i & 1) * 16384;
        char* kstage = LB + ((i & 1) ^ 1) * 16384;
        const int nkc = ((i + 1) & 15) * 128;

        __syncthreads();  // FULL: K(i)/V(i) gloads landed

        // ---- stores of p(i-1) ----
        if (i > 0) {
            const int pkc = kc - 128;
#pragma unroll
            for (int rr = 0; rr < 8; rr++) {
                const int r = 2 * rr + (lane >> 5);
                f16x4 ev = *(const f16x4*)(ES + r * 256 + (((lane & 31) * 8) ^ ((r & 7) << 4)));
                f32x4 o;
                o[0] = (float)ev[0]; o[1] = (float)ev[1];
                o[2] = (float)ev[2]; o[3] = (float)ev[3];
                *(f32x4*)(arow0 + (long long)r * NSEQ + pkc + (lane & 31) * 4) = o;
            }
            __asm__ volatile("s_waitcnt lgkmcnt(0)" ::: "memory"); // ES reads done before overwrite
            __builtin_amdgcn_sched_barrier(0);
        }

        // ---- stage K(i+1) -> kstage ----
#pragma unroll
        for (int q = 0; q < 2; q++) {
            int r = w * 16 + q * 8 + krl;
            gload16(Kg + (long long)(nkc + r) * 512 + ((kcb ^ ((r & 7) << 4)) >> 1),
                    kstage + (w * 16 + q * 8) * 128);
        }

        // ---- QK chunk i -> p -> ES ----
#pragma unroll
        for (int t = 0; t < 8; t++) {
            const char* kb = kbuf + (t * 16 + c) * 128;
            f16x8 kb0 = *(const f16x8*)(kb + ((g * 16) ^ swz));
            f16x8 kb1 = *(const f16x8*)(kb + ((64 + g * 16) ^ swz));
            f32x4 acc = {0.f, 0.f, 0.f, 0.f};
            acc = MFMA16(kb0, qa, acc);
            acc = MFMA16(kb1, qb_, acc);
            float p0 = __expf(fminf(acc[0] * 0.125f, 11.f)) * inv;
            float p1 = __expf(fminf(acc[1] * 0.125f, 11.f)) * inv;
            float p2 = __expf(fminf(acc[2] * 0.125f, 11.f)) * inv;
            float p3 = __expf(fminf(acc[3] * 0.125f, 11.f)) * inv;
            f16x2 a01; a01[0] = (_Float16)p0; a01[1] = (_Float16)p1;
            f16x2 a23; a23[0] = (_Float16)p2; a23[1] = (_Float16)p3;
            int b0 = c * 256 + ((t * 32 + g * 8) ^ swz);
            *(f16x2*)(ES + b0) = a01;
            *(f16x2*)(ES + b0 + 4) = a23;
        }
        __asm__ volatile("s_waitcnt lgkmcnt(0)" ::: "memory");
        f16x8 pa0 = *(const f16x8*)(ES + c * 256 + ((g * 16) ^ swz));
        f16x8 pa1 = *(const f16x8*)(ES + c * 256 + ((64 + g * 16) ^ swz));
        f16x8 pa2 = *(const f16x8*)(ES + c * 256 + ((128 + g * 16) ^ swz));
        f16x8 pa3 = *(const f16x8*)(ES + c * 256 + ((192 + g * 16) ^ swz));

        // ---- PV all 128 cols (V(i) from Vbuf) ----
#pragma unroll
        for (int dt = 0; dt < 4; dt++) {
            const char* vrow = LB + 32768 + (dt * 16 + c) * 256;
            f16x8 vb0 = *(const f16x8*)(vrow + ((g * 16) ^ swz));
            f16x8 vb1 = *(const f16x8*)(vrow + ((64 + g * 16) ^ swz));
            f16x8 vb2 = *(const f16x8*)(vrow + ((128 + g * 16) ^ swz));
            f16x8 vb3 = *(const f16x8*)(vrow + ((192 + g * 16) ^ swz));
            opv[dt] = MFMA16(pa0, vb0, opv[dt]);
            opv[dt] = MFMA16(pa1, vb1, opv[dt]);
            opv[dt] = MFMA16(pa2, vb2, opv[dt]);
            opv[dt] = MFMA16(pa3, vb3, opv[dt]);
        }

        // ---- lgkm-only barrier (no vmcnt drain) ----
        __asm__ volatile("s_waitcnt lgkmcnt(0)" ::: "memory");
        __builtin_amdgcn_s_barrier();

        // ---- stage V(i+1) -> Vbuf ----
#pragma unroll
        for (int q = 0; q < 2; q++) {
            int j = w + q * 8;
            int d = j * 4 + vrl;
            gload16(Vg + (long long)d * NSEQ + nkc + ((vcb ^ ((d & 7) << 4)) >> 1),
                    LB + 32768 + j * 1024);
        }
    }

    // ---- epilogue: stores of p(15) ----
    {
        const int pkc = 15 * 128;
#pragma unroll
        for (int rr = 0; rr < 8; rr++) {
            const int r = 2 * rr + (lane >> 5);
            f16x4 ev = *(const f16x4*)(ES + r * 256 + (((lane & 31) * 8) ^ ((r & 7) << 4)));
            f32x4 o;
            o[0] = (float)ev[0]; o[1] = (float)ev[1];
            o[2] = (float)ev[2]; o[3] = (float)ev[3];
            *(f32x4*)(arow0 + (long long)r * NSEQ + pkc + (lane & 31) * 4) = o;
        }
    }

    // ---- AV epilogue (p already normalized) ----
#pragma unroll
    for (int dt = 0; dt < 4; dt++)
#pragma unroll
        for (int j = 0; j < 4; j++)
            AVh[(long long)(q0 + w * 16 + 4 * g + j) * DMODEL + h * 64 + dt * 16 + c] =
                (_Float16)opv[dt][j];
}

extern "C" void kernel_launch(void* const* d_in, const int* in_sizes, int n_in,
                              void* d_out, int out_size, void* d_ws, size_t ws_size,
                              hipStream_t stream) {
    const float* x  = (const float*)d_in[0];
    const float* Wq = (const float*)d_in[1];
    const float* Wk = (const float*)d_in[2];
    const float* Wv = (const float*)d_in[3];
    const float* Wo = (const float*)d_in[4];
    float* out = (float*)d_out;
    float* attn = out + (size_t)NSEQ * DMODEL;

    char* w = (char*)d_ws;
    auto alloc = [&](size_t bytes) { char* p = w; w += (bytes + 255) & ~(size_t)255; return p; };
    const size_t MD = (size_t)NSEQ * DMODEL;        // 4M elems
    const size_t MKV = (size_t)NSEQ * NKV * DK;     // 1M elems
    _Float16* xh    = (_Float16*)alloc(MD * 2);
    _Float16* WqkvT = (_Float16*)alloc((size_t)3072 * 2048 * 2);
    _Float16* WoT   = (_Float16*)alloc(MD * 2);
    float2*   cs    = (float2*)alloc((size_t)NSEQ * 32 * sizeof(float2));
    _Float16* QKV   = (_Float16*)alloc((size_t)2048 * 3072 * 2);
    _Float16* Kh    = (_Float16*)alloc(MKV * 2);
    _Float16* Vt    = (_Float16*)alloc(MKV * 2);
    float*    Sinv  = (float*)alloc((size_t)NHEADS * NSEQ * 4);
    _Float16* AVh   = xh;   // reuse (xh dead after QKV projection)

    prep_weights<<<dim3(64, 64, 5), dim3(32, 8), 0, stream>>>(
        x, Wq, Wk, Wv, Wo, xh, WqkvT, WoT);
    rope_table<<<256, 256, 0, stream>>>(cs);

    // fused QKV projection: [2048][2048] @ [3072][2048]^T -> [2048][3072]
    gemm_lds3<128, 64, 4, 2, _Float16><<<dim3(48, 16), 256, 0, stream>>>(
        xh, WqkvT, QKV, DMODEL, DMODEL, DMODEL, 3072);

    rope_apply16<<<2048, 256, 0, stream>>>(QKV, cs, Kh);
    transpose16p<<<dim3(16, 64), dim3(32, 8), 0, stream>>>(QKV + 2560, Vt, NSEQ, 512, 3072);

    attn_sums<<<dim3(NSEQ / 128, NHEADS), 512, 0, stream>>>(QKV, cs, Kh, Sinv);

    fused_attn<<<dim3(NSEQ / 128, NHEADS), 512, 0, stream>>>(QKV, cs, Kh, Vt, Sinv, attn, AVh);

    gemm_lds3<128, 64, 4, 2, float><<<dim3(32, 16), 256, 0, stream>>>(
        AVh, WoT, out, DMODEL, DMODEL, DMODEL, DMODEL);
}

// Round 17
// 245.819 us; speedup vs baseline: 2.1913x; 1.0447x over previous
//
#include <hip/hip_runtime.h>

typedef _Float16 f16x8 __attribute__((ext_vector_type(8)));
typedef _Float16 f16x4 __attribute__((ext_vector_type(4)));
typedef _Float16 f16x2 __attribute__((ext_vector_type(2)));
typedef float f32x4 __attribute__((ext_vector_type(4)));

#define NSEQ 2048
#define DMODEL 2048
#define NHEADS 32
#define NKV 8
#define DK 64
#define MFMA16(a, b, c) __builtin_amdgcn_mfma_f32_16x16x32_f16(a, b, c, 0, 0, 0)

// async global->LDS, 16B per lane; LDS dest is wave-uniform base + lane*16
__device__ __forceinline__ void gload16(const void* g, void* l) {
    __builtin_amdgcn_global_load_lds(
        (const __attribute__((address_space(1))) void*)g,
        (__attribute__((address_space(3))) void*)l, 16, 0, 0);
}

// ---------------- fused prep: x f32->f16 copy + 4 weight transposes ----------------
__global__ __launch_bounds__(256) void prep_weights(
    const float* __restrict__ x,  const float* __restrict__ Wq,
    const float* __restrict__ Wk, const float* __restrict__ Wv,
    const float* __restrict__ Wo, _Float16* __restrict__ xh,
    _Float16* __restrict__ WqkvT, _Float16* __restrict__ WoT) {
    const int z = blockIdx.z;
    const int tx = threadIdx.x, ty = threadIdx.y; // (32,8)
    if (z == 0) {
        int c0 = blockIdx.x * 32, r0 = blockIdx.y * 32;
#pragma unroll
        for (int i = 0; i < 4; i++) {
            int r = r0 + ty + i * 8;
            xh[(long long)r * DMODEL + c0 + tx] = (_Float16)x[(long long)r * DMODEL + c0 + tx];
        }
        return;
    }
    const float* in; _Float16* out; int C;
    if (z == 1)      { in = Wq; out = WqkvT;                        C = 2048; }
    else if (z == 2) { in = Wk; out = WqkvT + (size_t)2048 * 2048;  C = 512;  }
    else if (z == 3) { in = Wv; out = WqkvT + (size_t)2560 * 2048;  C = 512;  }
    else             { in = Wo; out = WoT;                          C = 2048; }
    int c0 = blockIdx.x * 32, r0 = blockIdx.y * 32;
    if (c0 >= C) return;
    __shared__ float tile[32][33];
#pragma unroll
    for (int i = 0; i < 4; i++) {
        int r = r0 + ty + i * 8;
        tile[ty + i * 8][tx] = in[(long long)r * C + c0 + tx];
    }
    __syncthreads();
#pragma unroll
    for (int i = 0; i < 4; i++) {
        int c = c0 + ty + i * 8;
        out[(long long)c * 2048 + r0 + tx] = (_Float16)tile[tx][ty + i * 8];
    }
}

// ---------------- transpose f16 [R][C] (row pitch) -> f16 [C][R] ----------------
__global__ __launch_bounds__(256) void transpose16p(const _Float16* __restrict__ in,
                                                    _Float16* __restrict__ out,
                                                    int R, int C, int pitch) {
    __shared__ _Float16 tile[32][34];
    int c0 = blockIdx.x * 32, r0 = blockIdx.y * 32;
    int tx = threadIdx.x, ty = threadIdx.y; // (32,8)
#pragma unroll
    for (int i = 0; i < 4; i++) {
        int r = r0 + ty + i * 8;
        tile[ty + i * 8][tx] = in[(long long)r * pitch + c0 + tx];
    }
    __syncthreads();
#pragma unroll
    for (int i = 0; i < 4; i++) {
        int c = c0 + ty + i * 8;
        out[(long long)c * R + r0 + tx] = tile[tx][ty + i * 8];
    }
}

// ---------------- RoPE cos/sin table ----------------
__global__ void rope_table(float2* __restrict__ cs) {
    int idx = blockIdx.x * blockDim.x + threadIdx.x; // 65536 total
    int n = idx >> 5, j = idx & 31;
    float e = (2.0f * j) / 64.0f;
    float invf = 1.0f / powf(10000.0f, e);
    float ang = (float)n * invf;
    float2 v; v.x = cosf(ang); v.y = sinf(ang);
    cs[idx] = v;
}

// ---------------- RoPE apply for K: reads K cols of QKV [2048][3072], writes Kh [2048][512] --
__global__ void rope_apply16(const _Float16* __restrict__ QKV, const float2* __restrict__ cs,
                             _Float16* __restrict__ out) {
    int idx = blockIdx.x * blockDim.x + threadIdx.x; // 2048*256
    int n = idx >> 8, rem = idx & 255;
    int hk = rem >> 5, j = rem & 31;
    float2 c = cs[n * 32 + j];
    const _Float16* in = QKV + (long long)n * 3072 + 2048 + hk * 64;
    float x1 = (float)in[j], x2 = (float)in[j + 32];
    long long ob = (long long)n * 512 + hk * 64;
    out[ob + j]      = (_Float16)(x1 * c.x - x2 * c.y);
    out[ob + j + 32] = (_Float16)(x2 * c.x + x1 * c.y);
}

// ---------------- GEMM v3: double-buffered LDS, ONE barrier per K-step, XCD swizzle --------
template <int BM, int BN, int MF, int NF, typename OutT>
__global__ __launch_bounds__(256) void gemm_lds3(const _Float16* __restrict__ Ap,
                                                 const _Float16* __restrict__ Bt,
                                                 OutT* __restrict__ C,
                                                 int K, int lda, int ldb, int ldc) {
    __shared__ __align__(16) _Float16 As[2][BM * 64];
    __shared__ __align__(16) _Float16 Bs[2][BN * 64];

    const int tid = threadIdx.x;
    const int lane = tid & 63, w = tid >> 6;
    constexpr int WC = BN / (NF * 16);
    const int wr = w / WC, wc = w % WC;
    const int wm = wr * MF * 16, wn = wc * NF * 16;
    const int am = lane & 15;
    const int g = lane >> 4;
    const int aswz = (am & 7) << 4;

    // bijective XCD remap of flattened block id (nwg % 8 == 0 for all our grids)
    const int nwg = gridDim.x * gridDim.y;
    int fid = blockIdx.y * gridDim.x + blockIdx.x;
    fid = (fid & 7) * (nwg >> 3) + (fid >> 3);
    const int bx = fid % gridDim.x, by = fid / gridDim.x;

    f32x4 acc[MF][NF] = {};

    const long long a_row0 = (long long)by * BM * lda;
    const long long b_row0 = (long long)bx * BN * ldb;

    const int srow = lane >> 3;        // staging: row within 8-row group
    const int scolb = (lane & 7) * 16; // staging: byte col within 128B row

    auto stage = [&](int kt, int buf) {
#pragma unroll
        for (int q = 0; q < BM / 32; q++) {
            const int rA = w * (BM / 4) + q * 8;
            const int r = rA + srow;
            gload16(Ap + a_row0 + (long long)r * lda + kt + ((scolb ^ ((r & 7) << 4)) >> 1),
                    &As[buf][rA * 64]);
        }
#pragma unroll
        for (int q = 0; q < BN / 32; q++) {
            const int rB = w * (BN / 4) + q * 8;
            const int r = rB + srow;
            gload16(Bt + b_row0 + (long long)r * ldb + kt + ((scolb ^ ((r & 7) << 4)) >> 1),
                    &Bs[buf][rB * 64]);
        }
    };

    stage(0, 0);
    int cur = 0;

    for (int kt = 0; kt < K; kt += 64) {
        __syncthreads();                 // drains stage(kt) — issued one full phase ago
        if (kt + 64 < K) stage(kt + 64, cur ^ 1);

#pragma unroll
        for (int ks = 0; ks < 2; ks++) {
            const int koff = ((ks * 64 + g * 16) ^ aswz) >> 1; // byte->half
            f16x8 af[MF], bf[NF];
#pragma unroll
            for (int m = 0; m < MF; m++)
                af[m] = *(const f16x8*)&As[cur][(wm + m * 16 + am) * 64 + koff];
#pragma unroll
            for (int n = 0; n < NF; n++)
                bf[n] = *(const f16x8*)&Bs[cur][(wn + n * 16 + am) * 64 + koff];
#pragma unroll
            for (int m = 0; m < MF; m++)
#pragma unroll
                for (int n = 0; n < NF; n++)
                    acc[m][n] = MFMA16(af[m], bf[n], acc[m][n]);
        }
        cur ^= 1;
    }

    const int rb = by * BM + wm + (lane >> 4) * 4;
    const int cb = bx * BN + wn + am;
#pragma unroll
    for (int m = 0; m < MF; m++)
#pragma unroll
        for (int n = 0; n < NF; n++)
#pragma unroll
            for (int j = 0; j < 4; j++)
                C[(long long)(rb + m * 16 + j) * ldc + cb + n * 16] = (OutT)acc[m][n][j];
}

// ---------------- kernel A: split-K row sums -> Spart[2][32][2048] ----------------
// z = blockIdx.z owns kcols [z*1024, +1024) (8 chunks); 4 blocks/CU (100% occupancy).
// Deterministic: each half writes its own slot; fused_attn sums the two.
__global__ __launch_bounds__(512) void attn_sums(
    const _Float16* __restrict__ QKV,  // [2048][3072] (Q cols 0..2047, pre-rope)
    const float2*  __restrict__ cs,    // [2048][32]
    const _Float16* __restrict__ Kh,   // [2048][512] roped
    float* __restrict__ Spart)         // [2][32][2048]
{
    __shared__ __align__(16) char LB[32768]; // Kbuf[2] 2x16KB

    const int h = blockIdx.y, q0 = blockIdx.x * 128, z = blockIdx.z;
    const int kvh = h >> 2;
    const int tid = threadIdx.x, lane = tid & 63, w = tid >> 6;
    const int g = lane >> 4, c = lane & 15;
    const int swz = (c & 7) << 4;
    const int kbase = z * 1024;

    const _Float16* qp = QKV + (long long)(q0 + w * 16 + c) * 3072 + h * 64;
    f16x8 q0v = *(const f16x8*)(qp + g * 8);
    f16x8 q1v = *(const f16x8*)(qp + 32 + g * 8);
    const float2* csp = cs + (q0 + w * 16 + c) * 32 + g * 8;
    f16x8 qa, qb_;
#pragma unroll
    for (int e = 0; e < 8; e++) {
        float2 cv = csp[e];
        float x1 = (float)q0v[e], x2 = (float)q1v[e];
        qa[e]  = (_Float16)(x1 * cv.x - x2 * cv.y);
        qb_[e] = (_Float16)(x2 * cv.x + x1 * cv.y);
    }

    const _Float16* Kg = Kh + kvh * 64;
    const int krl = lane >> 3, kcb = (lane & 7) * 16;

#pragma unroll
    for (int q = 0; q < 2; q++) {
        int r = kbase + w * 16 + q * 8 + krl;
        gload16(Kg + (long long)r * 512 + ((kcb ^ ((r & 7) << 4)) >> 1),
                LB + (w * 16 + q * 8) * 128);
    }
    __syncthreads();

    float l = 0.f;
    for (int i = 0; i < 8; i++) {
        const char* kbuf = LB + (i & 1) * 16384;
        char* kstage = LB + ((i & 1) ^ 1) * 16384;
        const int nkc = kbase + ((i + 1) & 7) * 128;
#pragma unroll
        for (int q = 0; q < 2; q++) {
            int r = nkc + w * 16 + q * 8 + krl;
            gload16(Kg + (long long)r * 512 + ((kcb ^ ((r & 7) << 4)) >> 1),
                    kstage + (w * 16 + q * 8) * 128);
        }
#pragma unroll
        for (int t = 0; t < 8; t++) {
            const char* kb = kbuf + (t * 16 + c) * 128;
            f16x8 kb0 = *(const f16x8*)(kb + ((g * 16) ^ swz));
            f16x8 kb1 = *(const f16x8*)(kb + ((64 + g * 16) ^ swz));
            f32x4 acc = {0.f, 0.f, 0.f, 0.f};
            acc = MFMA16(kb0, qa, acc);
            acc = MFMA16(kb1, qb_, acc);
            l += __expf(fminf(acc[0] * 0.125f, 11.f)) + __expf(fminf(acc[1] * 0.125f, 11.f)) +
                 __expf(fminf(acc[2] * 0.125f, 11.f)) + __expf(fminf(acc[3] * 0.125f, 11.f));
        }
        __syncthreads();
    }
    l += __shfl_xor(l, 16, 64);
    l += __shfl_xor(l, 32, 64);
    if (lane < 16)
        Spart[((long long)z * NHEADS + h) * NSEQ + q0 + w * 16 + c] = l;
}

// ---------------- fused attention v11: v10 + nontemporal attn stores + Spart inv ----------
__global__ __launch_bounds__(512) void fused_attn(
    const _Float16* __restrict__ QKV,  // [2048][3072], Q = cols 0..2047 (pre-rope)
    const float2*  __restrict__ cs,    // [2048][32]
    const _Float16* __restrict__ Kh,   // [2048][512] roped
    const _Float16* __restrict__ Vt,   // [512][2048]
    const float* __restrict__ Spart,   // [2][32][2048]
    float* __restrict__ attn,          // [32][2048][2048]
    _Float16* __restrict__ AVh)        // [2048][2048]
{
    __shared__ __align__(16) char LB[81920];

    const int h = blockIdx.y, q0 = blockIdx.x * 128;
    const int kvh = h >> 2;
    const int tid = threadIdx.x, lane = tid & 63, w = tid >> 6;
    const int g = lane >> 4, c = lane & 15;
    const int swz = (c & 7) << 4;

    // ---- Q fragment + in-register RoPE ----
    const _Float16* qp = QKV + (long long)(q0 + w * 16 + c) * 3072 + h * 64;
    f16x8 q0v = *(const f16x8*)(qp + g * 8);
    f16x8 q1v = *(const f16x8*)(qp + 32 + g * 8);
    const float2* csp = cs + (q0 + w * 16 + c) * 32 + g * 8;
    f16x8 qa, qb_;
#pragma unroll
    for (int e = 0; e < 8; e++) {
        float2 cv = csp[e];
        float x1 = (float)q0v[e], x2 = (float)q1v[e];
        qa[e]  = (_Float16)(x1 * cv.x - x2 * cv.y);
        qb_[e] = (_Float16)(x2 * cv.x + x1 * cv.y);
    }

    const long long qidx = (long long)h * NSEQ + q0 + w * 16 + c;
    const float inv = 1.0f / (Spart[qidx] + Spart[(long long)NHEADS * NSEQ + qidx]);

    const _Float16* Kg = Kh + kvh * 64;
    const _Float16* Vg = Vt + (long long)(kvh * 64) * NSEQ;
    char* ES = LB + 49152 + w * 4096;  // 16 rows x 256B, wave-private
    float* arow0 = attn + ((long long)h * NSEQ + q0 + w * 16) * NSEQ;

    const int krl = lane >> 3, kcb = (lane & 7) * 16;
    const int vrl = lane >> 4, vcb = (lane & 15) * 16;

    // ---- prologue: stage K(0) -> Kbuf[0], V(0) -> Vbuf ----
#pragma unroll
    for (int q = 0; q < 2; q++) {
        int r = w * 16 + q * 8 + krl;
        gload16(Kg + (long long)r * 512 + ((kcb ^ ((r & 7) << 4)) >> 1),
                LB + (w * 16 + q * 8) * 128);
    }
#pragma unroll
    for (int q = 0; q < 2; q++) {
        int j = w + q * 8;
        int d = j * 4 + vrl;
        gload16(Vg + (long long)d * NSEQ + ((vcb ^ ((d & 7) << 4)) >> 1),
                LB + 32768 + j * 1024);
    }

    f32x4 opv[4] = {};

    for (int i = 0; i < 16; i++) {
        const int kc = i * 128;
        const char* kbuf = LB + (i & 1) * 16384;
        char* kstage = LB + ((i & 1) ^ 1) * 16384;
        const int nkc = ((i + 1) & 15) * 128;

        __syncthreads();  // FULL: K(i)/V(i) gloads landed

        // ---- stores of p(i-1): nontemporal (512B-contiguous runs = full lines) ----
        if (i > 0) {
            const int pkc = kc - 128;
#pragma unroll
            for (int rr = 0; rr < 8; rr++) {
                const int r = 2 * rr + (lane >> 5);
                f16x4 ev = *(const f16x4*)(ES + r * 256 + (((lane & 31) * 8) ^ ((r & 7) << 4)));
                f32x4 o;
                o[0] = (float)ev[0]; o[1] = (float)ev[1];
                o[2] = (float)ev[2]; o[3] = (float)ev[3];
                __builtin_nontemporal_store(o, (f32x4*)(arow0 + (long long)r * NSEQ + pkc + (lane & 31) * 4));
            }
            __asm__ volatile("s_waitcnt lgkmcnt(0)" ::: "memory"); // ES reads done before overwrite
            __builtin_amdgcn_sched_barrier(0);
        }

        // ---- stage K(i+1) -> kstage ----
#pragma unroll
        for (int q = 0; q < 2; q++) {
            int r = w * 16 + q * 8 + krl;
            gload16(Kg + (long long)(nkc + r) * 512 + ((kcb ^ ((r & 7) << 4)) >> 1),
                    kstage + (w * 16 + q * 8) * 128);
        }

        // ---- QK chunk i -> p -> ES ----
#pragma unroll
        for (int t = 0; t < 8; t++) {
            const char* kb = kbuf + (t * 16 + c) * 128;
            f16x8 kb0 = *(const f16x8*)(kb + ((g * 16) ^ swz));
            f16x8 kb1 = *(const f16x8*)(kb + ((64 + g * 16) ^ swz));
            f32x4 acc = {0.f, 0.f, 0.f, 0.f};
            acc = MFMA16(kb0, qa, acc);
            acc = MFMA16(kb1, qb_, acc);
            float p0 = __expf(fminf(acc[0] * 0.125f, 11.f)) * inv;
            float p1 = __expf(fminf(acc[1] * 0.125f, 11.f)) * inv;
            float p2 = __expf(fminf(acc[2] * 0.125f, 11.f)) * inv;
            float p3 = __expf(fminf(acc[3] * 0.125f, 11.f)) * inv;
            f16x2 a01; a01[0] = (_Float16)p0; a01[1] = (_Float16)p1;
            f16x2 a23; a23[0] = (_Float16)p2; a23[1] = (_Float16)p3;
            int b0 = c * 256 + ((t * 32 + g * 8) ^ swz);
            *(f16x2*)(ES + b0) = a01;
            *(f16x2*)(ES + b0 + 4) = a23;
        }
        __asm__ volatile("s_waitcnt lgkmcnt(0)" ::: "memory");
        f16x8 pa0 = *(const f16x8*)(ES + c * 256 + ((g * 16) ^ swz));
        f16x8 pa1 = *(const f16x8*)(ES + c * 256 + ((64 + g * 16) ^ swz));
        f16x8 pa2 = *(const f16x8*)(ES + c * 256 + ((128 + g * 16) ^ swz));
        f16x8 pa3 = *(const f16x8*)(ES + c * 256 + ((192 + g * 16) ^ swz));

        // ---- PV all 128 cols (V(i) from Vbuf) ----
#pragma unroll
        for (int dt = 0; dt < 4; dt++) {
            const char* vrow = LB + 32768 + (dt * 16 + c) * 256;
            f16x8 vb0 = *(const f16x8*)(vrow + ((g * 16) ^ swz));
            f16x8 vb1 = *(const f16x8*)(vrow + ((64 + g * 16) ^ swz));
            f16x8 vb2 = *(const f16x8*)(vrow + ((128 + g * 16) ^ swz));
            f16x8 vb3 = *(const f16x8*)(vrow + ((192 + g * 16) ^ swz));
            opv[dt] = MFMA16(pa0, vb0, opv[dt]);
            opv[dt] = MFMA16(pa1, vb1, opv[dt]);
            opv[dt] = MFMA16(pa2, vb2, opv[dt]);
            opv[dt] = MFMA16(pa3, vb3, opv[dt]);
        }

        // ---- lgkm-only barrier (no vmcnt drain) ----
        __asm__ volatile("s_waitcnt lgkmcnt(0)" ::: "memory");
        __builtin_amdgcn_s_barrier();

        // ---- stage V(i+1) -> Vbuf ----
#pragma unroll
        for (int q = 0; q < 2; q++) {
            int j = w + q * 8;
            int d = j * 4 + vrl;
            gload16(Vg + (long long)d * NSEQ + nkc + ((vcb ^ ((d & 7) << 4)) >> 1),
                    LB + 32768 + j * 1024);
        }
    }

    // ---- epilogue: stores of p(15) ----
    {
        const int pkc = 15 * 128;
#pragma unroll
        for (int rr = 0; rr < 8; rr++) {
            const int r = 2 * rr + (lane >> 5);
            f16x4 ev = *(const f16x4*)(ES + r * 256 + (((lane & 31) * 8) ^ ((r & 7) << 4)));
            f32x4 o;
            o[0] = (float)ev[0]; o[1] = (float)ev[1];
            o[2] = (float)ev[2]; o[3] = (float)ev[3];
            __builtin_nontemporal_store(o, (f32x4*)(arow0 + (long long)r * NSEQ + pkc + (lane & 31) * 4));
        }
    }

    // ---- AV epilogue (p already normalized) ----
#pragma unroll
    for (int dt = 0; dt < 4; dt++)
#pragma unroll
        for (int j = 0; j < 4; j++)
            AVh[(long long)(q0 + w * 16 + 4 * g + j) * DMODEL + h * 64 + dt * 16 + c] =
                (_Float16)opv[dt][j];
}

extern "C" void kernel_launch(void* const* d_in, const int* in_sizes, int n_in,
                              void* d_out, int out_size, void* d_ws, size_t ws_size,
                              hipStream_t stream) {
    const float* x  = (const float*)d_in[0];
    const float* Wq = (const float*)d_in[1];
    const float* Wk = (const float*)d_in[2];
    const float* Wv = (const float*)d_in[3];
    const float* Wo = (const float*)d_in[4];
    float* out = (float*)d_out;
    float* attn = out + (size_t)NSEQ * DMODEL;

    char* w = (char*)d_ws;
    auto alloc = [&](size_t bytes) { char* p = w; w += (bytes + 255) & ~(size_t)255; return p; };
    const size_t MD = (size_t)NSEQ * DMODEL;        // 4M elems
    const size_t MKV = (size_t)NSEQ * NKV * DK;     // 1M elems
    _Float16* xh    = (_Float16*)alloc(MD * 2);
    _Float16* WqkvT = (_Float16*)alloc((size_t)3072 * 2048 * 2);
    _Float16* WoT   = (_Float16*)alloc(MD * 2);
    float2*   cs    = (float2*)alloc((size_t)NSEQ * 32 * sizeof(float2));
    _Float16* QKV   = (_Float16*)alloc((size_t)2048 * 3072 * 2);
    _Float16* Kh    = (_Float16*)alloc(MKV * 2);
    _Float16* Vt    = (_Float16*)alloc(MKV * 2);
    float*    Spart = (float*)alloc((size_t)2 * NHEADS * NSEQ * 4);
    _Float16* AVh   = xh;   // reuse (xh dead after QKV projection)

    prep_weights<<<dim3(64, 64, 5), dim3(32, 8), 0, stream>>>(
        x, Wq, Wk, Wv, Wo, xh, WqkvT, WoT);
    rope_table<<<256, 256, 0, stream>>>(cs);

    // fused QKV projection: [2048][2048] @ [3072][2048]^T -> [2048][3072]
    gemm_lds3<128, 64, 4, 2, _Float16><<<dim3(48, 16), 256, 0, stream>>>(
        xh, WqkvT, QKV, DMODEL, DMODEL, DMODEL, 3072);

    rope_apply16<<<2048, 256, 0, stream>>>(QKV, cs, Kh);
    transpose16p<<<dim3(16, 64), dim3(32, 8), 0, stream>>>(QKV + 2560, Vt, NSEQ, 512, 3072);

    attn_sums<<<dim3(NSEQ / 128, NHEADS, 2), 512, 0, stream>>>(QKV, cs, Kh, Spart);

    fused_attn<<<dim3(NSEQ / 128, NHEADS), 512, 0, stream>>>(QKV, cs, Kh, Vt, Spart, attn, AVh);

    gemm_lds3<128, 64, 4, 2, float><<<dim3(32, 16), 256, 0, stream>>>(
        AVh, WoT, out, DMODEL, DMODEL, DMODEL, DMODEL);
}